// Round 1
// baseline (1600.156 us; speedup 1.0000x reference)
//
#include <hip/hip_runtime.h>
#include <math.h>

#define N_NODES 50000
#define E_ORIG  500000
#define E_TOT   550000
#define CAPE    128   // per-node LDS edge cache (max degree ~35 for this graph; >CAPE falls back to recompute)

// ------------------------------------------------------------------
// CSR build (group edges by destination node)
// ------------------------------------------------------------------
__global__ void k_zero(int* __restrict__ p, int n) {
    int i = blockIdx.x * blockDim.x + threadIdx.x;
    if (i < n) p[i] = 0;
}

__global__ void k_count(const int* __restrict__ ei, int* __restrict__ deg) {
    int e = blockIdx.x * blockDim.x + threadIdx.x;
    if (e >= E_TOT) return;
    int d = (e < E_ORIG) ? ei[E_ORIG + e] : (e - E_ORIG);
    atomicAdd(&deg[d], 1);
}

// single-block exclusive scan over deg[N_NODES] -> offsets[N_NODES+1], cur copy
__global__ __launch_bounds__(1024) void k_scan(const int* __restrict__ deg,
                                               int* __restrict__ offsets,
                                               int* __restrict__ cur) {
    const int T = 1024, CH = 49; // 1024*49 = 50176 >= 50000
    __shared__ int sums[T];
    int t = threadIdx.x;
    int beg = t * CH, end = min(beg + CH, N_NODES);
    int s = 0;
    for (int i = beg; i < end; i++) s += deg[i];
    sums[t] = s;
    __syncthreads();
    for (int offn = 1; offn < T; offn <<= 1) {
        int v = (t >= offn) ? sums[t - offn] : 0;
        __syncthreads();
        sums[t] += v;
        __syncthreads();
    }
    int run = (t == 0) ? 0 : sums[t - 1];
    for (int i = beg; i < end; i++) {
        offsets[i] = run;
        cur[i] = run;
        run += deg[i];
    }
    if (t == T - 1) offsets[N_NODES] = sums[T - 1];
}

__global__ void k_scatter(const int* __restrict__ ei, int* __restrict__ cur,
                          int* __restrict__ csr_src) {
    int e = blockIdx.x * blockDim.x + threadIdx.x;
    if (e >= E_TOT) return;
    int s, d;
    if (e < E_ORIG) { s = ei[e]; d = ei[E_ORIG + e]; }
    else            { s = e - E_ORIG; d = s; }
    int slot = atomicAdd(&cur[d], 1);
    csr_src[slot] = s;
}

// ------------------------------------------------------------------
// GEMM (X[N,K] @ W[K,256]) + fused attention-coefficient epilogue.
// One thread per output column; 64 rows per block. X addresses are
// wave-uniform -> scalar loads; W chunk cached in VGPRs.
// NH=8: per-32-lane-segment reduce (e_src/e_dst per head).
// NH=1: full-block reduce.
// ------------------------------------------------------------------
template <int K, int NH>
__global__ __launch_bounds__(256) void k_gemm_attn(
    const float* __restrict__ X, const float* __restrict__ W,
    const float* __restrict__ a_src, const float* __restrict__ a_dst,
    float* __restrict__ H, float* __restrict__ es, float* __restrict__ ed) {
    constexpr int ROWS = 64;
    constexpr int KC = 32;
    int t = threadIdx.x;
    int row0 = blockIdx.x * ROWS;

    float acc[ROWS];
#pragma unroll
    for (int r = 0; r < ROWS; r++) acc[r] = 0.f;

    for (int kc = 0; kc < K; kc += KC) {
        float wreg[KC];
#pragma unroll
        for (int k = 0; k < KC; k++) wreg[k] = W[(size_t)(kc + k) * 256 + t];
#pragma unroll
        for (int r = 0; r < ROWS; r++) {
            int row = row0 + r;
            if (row >= N_NODES) row = N_NODES - 1;  // uniform clamp, store guarded later
            const float* xr = X + (size_t)row * K + kc;
            float a = acc[r];
#pragma unroll
            for (int k = 0; k < KC; k++) a = fmaf(xr[k], wreg[k], a);
            acc[r] = a;
        }
    }

    float asv = a_src[t], adv = a_dst[t];

    if constexpr (NH == 8) {
        int head = t >> 5;
#pragma unroll
        for (int r = 0; r < ROWS; r++) {
            int row = row0 + r;
            if (row < N_NODES) {
                H[(size_t)row * 256 + t] = acc[r];
                float ps = acc[r] * asv, pd = acc[r] * adv;
#pragma unroll
                for (int mk = 1; mk < 32; mk <<= 1) {
                    ps += __shfl_xor(ps, mk, 64);
                    pd += __shfl_xor(pd, mk, 64);
                }
                if ((t & 31) == 0) {
                    es[(size_t)row * 8 + head] = ps;
                    ed[(size_t)row * 8 + head] = pd;
                }
            }
        }
    } else {
        __shared__ float psrc[ROWS][4], pdst[ROWS][4];
        int w = t >> 6, lane = t & 63;
#pragma unroll
        for (int r = 0; r < ROWS; r++) {
            int row = row0 + r;
            if (row < N_NODES) H[(size_t)row * 256 + t] = acc[r];
            float ps = acc[r] * asv, pd = acc[r] * adv;
#pragma unroll
            for (int mk = 1; mk < 64; mk <<= 1) {
                ps += __shfl_xor(ps, mk, 64);
                pd += __shfl_xor(pd, mk, 64);
            }
            if (lane == 0) { psrc[r][w] = ps; pdst[r][w] = pd; }
        }
        __syncthreads();
        if (t < ROWS) {
            int row = row0 + t;
            if (row < N_NODES) {
                es[row] = psrc[t][0] + psrc[t][1] + psrc[t][2] + psrc[t][3];
                ed[row] = pdst[t][0] + pdst[t][1] + pdst[t][2] + pdst[t][3];
            }
        }
    }
}

// ------------------------------------------------------------------
// Layer-1 aggregation: softmax over incoming edges (8 heads), gather
// alpha-weighted source rows, +b1, ELU. One block per dst node.
// ------------------------------------------------------------------
__global__ __launch_bounds__(256) void k_agg1(
    const float* __restrict__ H1, const float* __restrict__ es,
    const float* __restrict__ ed, const int* __restrict__ offsets,
    const int* __restrict__ csr_src, const float* __restrict__ b1,
    float* __restrict__ out1) {
    int n = blockIdx.x;
    int t = threadIdx.x;
    int beg = offsets[n];
    int deg = offsets[n + 1] - beg;
    __shared__ int lsrc[CAPE];
    __shared__ float lalpha[CAPE * 8];
    __shared__ float sm[8], sd[8], sed[8];
    __shared__ float wred[4][8];

    if (t < 8) sed[t] = ed[(size_t)n * 8 + t];
    int ncap = deg < CAPE ? deg : CAPE;
    for (int i = t; i < ncap; i += 256) lsrc[i] = csr_src[beg + i];
    __syncthreads();

    int h = t & 7, slot = t >> 3;  // 32 edge slots x 8 heads
    // pass 1: per-head max
    float mx = -1e30f;
    for (int i = slot; i < deg; i += 32) {
        int s = (i < CAPE) ? lsrc[i] : csr_src[beg + i];
        float l = es[(size_t)s * 8 + h] + sed[h];
        l = l > 0.f ? l : 0.2f * l;
        mx = fmaxf(mx, l);
    }
#pragma unroll
    for (int mk = 8; mk < 64; mk <<= 1) mx = fmaxf(mx, __shfl_xor(mx, mk, 64));
    if ((t & 63) < 8) wred[t >> 6][h] = mx;
    __syncthreads();
    if (t < 8)
        sm[t] = fmaxf(fmaxf(wred[0][t], wred[1][t]), fmaxf(wred[2][t], wred[3][t]));
    __syncthreads();

    // pass 2: per-head sum of exp
    float mh = sm[h];
    float sum = 0.f;
    for (int i = slot; i < deg; i += 32) {
        int s = (i < CAPE) ? lsrc[i] : csr_src[beg + i];
        float l = es[(size_t)s * 8 + h] + sed[h];
        l = l > 0.f ? l : 0.2f * l;
        sum += expf(l - mh);
    }
#pragma unroll
    for (int mk = 8; mk < 64; mk <<= 1) sum += __shfl_xor(sum, mk, 64);
    if ((t & 63) < 8) wred[t >> 6][h] = sum;
    __syncthreads();
    if (t < 8) sd[t] = wred[0][t] + wred[1][t] + wred[2][t] + wred[3][t] + 1e-16f;
    __syncthreads();

    // alpha cache for the first CAPE edges
    for (int idx = t; idx < ncap * 8; idx += 256) {
        int i = idx >> 3, hh = idx & 7;
        int s = lsrc[i];
        float l = es[(size_t)s * 8 + hh] + sed[hh];
        l = l > 0.f ? l : 0.2f * l;
        lalpha[idx] = expf(l - sm[hh]) / sd[hh];
    }
    __syncthreads();

    // aggregate: thread t owns channel t (head = t>>5)
    int head = t >> 5;
    float accv = 0.f;
    for (int i = 0; i < deg; i++) {
        int s; float al;
        if (i < CAPE) { s = lsrc[i]; al = lalpha[i * 8 + head]; }
        else {
            s = csr_src[beg + i];
            float l = es[(size_t)s * 8 + head] + sed[head];
            l = l > 0.f ? l : 0.2f * l;
            al = expf(l - sm[head]) / sd[head];
        }
        accv += al * H1[(size_t)s * 256 + t];
    }
    float o = accv + b1[t];
    out1[(size_t)n * 256 + t] = o > 0.f ? o : expf(o) - 1.f;  // ELU
}

// ------------------------------------------------------------------
// Layer-2 aggregation: single head over 256 channels, +b2 -> d_out
// ------------------------------------------------------------------
__global__ __launch_bounds__(256) void k_agg2(
    const float* __restrict__ H2, const float* __restrict__ es,
    const float* __restrict__ ed, const int* __restrict__ offsets,
    const int* __restrict__ csr_src, const float* __restrict__ b2,
    float* __restrict__ out) {
    int n = blockIdx.x, t = threadIdx.x;
    int beg = offsets[n];
    int deg = offsets[n + 1] - beg;
    __shared__ int lsrc[CAPE];
    __shared__ float lalpha[CAPE];
    __shared__ float wredf[4];
    __shared__ float sstat[2];
    float edn = ed[n];
    int ncap = deg < CAPE ? deg : CAPE;
    for (int i = t; i < ncap; i += 256) lsrc[i] = csr_src[beg + i];
    __syncthreads();

    float mx = -1e30f;
    for (int i = t; i < deg; i += 256) {
        int s = (i < CAPE) ? lsrc[i] : csr_src[beg + i];
        float l = es[s] + edn; l = l > 0.f ? l : 0.2f * l;
        mx = fmaxf(mx, l);
    }
#pragma unroll
    for (int mk = 1; mk < 64; mk <<= 1) mx = fmaxf(mx, __shfl_xor(mx, mk, 64));
    if ((t & 63) == 0) wredf[t >> 6] = mx;
    __syncthreads();
    if (t == 0) sstat[0] = fmaxf(fmaxf(wredf[0], wredf[1]), fmaxf(wredf[2], wredf[3]));
    __syncthreads();
    float m0 = sstat[0];

    float sum = 0.f;
    for (int i = t; i < deg; i += 256) {
        int s = (i < CAPE) ? lsrc[i] : csr_src[beg + i];
        float l = es[s] + edn; l = l > 0.f ? l : 0.2f * l;
        sum += expf(l - m0);
    }
#pragma unroll
    for (int mk = 1; mk < 64; mk <<= 1) sum += __shfl_xor(sum, mk, 64);
    if ((t & 63) == 0) wredf[t >> 6] = sum;
    __syncthreads();
    if (t == 0) sstat[1] = wredf[0] + wredf[1] + wredf[2] + wredf[3] + 1e-16f;
    __syncthreads();
    float dn = sstat[1];

    for (int i = t; i < ncap; i += 256) {
        int s = lsrc[i];
        float l = es[s] + edn; l = l > 0.f ? l : 0.2f * l;
        lalpha[i] = expf(l - m0) / dn;
    }
    __syncthreads();

    float accv = 0.f;
    for (int i = 0; i < deg; i++) {
        int s; float al;
        if (i < CAPE) { s = lsrc[i]; al = lalpha[i]; }
        else {
            s = csr_src[beg + i];
            float l = es[s] + edn; l = l > 0.f ? l : 0.2f * l;
            al = expf(l - m0) / dn;
        }
        accv += al * H2[(size_t)s * 256 + t];
    }
    out[(size_t)n * 256 + t] = accv + b2[t];
}

// ------------------------------------------------------------------
extern "C" void kernel_launch(void* const* d_in, const int* in_sizes, int n_in,
                              void* d_out, int out_size, void* d_ws, size_t ws_size,
                              hipStream_t stream) {
    const float* x   = (const float*)d_in[0];
    const int*   ei  = (const int*)d_in[1];
    const float* W1  = (const float*)d_in[2];
    const float* as1 = (const float*)d_in[3];
    const float* ad1 = (const float*)d_in[4];
    const float* b1  = (const float*)d_in[5];
    const float* W2  = (const float*)d_in[6];
    const float* as2 = (const float*)d_in[7];
    const float* ad2 = (const float*)d_in[8];
    const float* b2  = (const float*)d_in[9];
    float* out = (float*)d_out;

    char* ws = (char*)d_ws;
    size_t off = 0;
    auto alloc = [&](size_t bytes) {
        void* p = ws + off;
        off = (off + bytes + 255) & ~(size_t)255;
        return p;
    };
    float* h_buf   = (float*)alloc((size_t)N_NODES * 256 * 4);  // h1, then h2
    float* out1    = (float*)alloc((size_t)N_NODES * 256 * 4);
    float* es1     = (float*)alloc((size_t)N_NODES * 8 * 4);
    float* ed1     = (float*)alloc((size_t)N_NODES * 8 * 4);
    float* es2     = (float*)alloc((size_t)N_NODES * 4);
    float* ed2     = (float*)alloc((size_t)N_NODES * 4);
    int*   deg     = (int*)alloc((size_t)N_NODES * 4);
    int*   offsets = (int*)alloc((size_t)(N_NODES + 1) * 4);
    int*   cur     = (int*)alloc((size_t)N_NODES * 4);
    int*   csr_src = (int*)alloc((size_t)E_TOT * 4);

    const int TB = 256;
    int gridN  = (N_NODES + TB - 1) / TB;
    int gridE  = (E_TOT + TB - 1) / TB;
    int gridG  = (N_NODES + 63) / 64;

    // CSR build
    k_zero<<<gridN, TB, 0, stream>>>(deg, N_NODES);
    k_count<<<gridE, TB, 0, stream>>>(ei, deg);
    k_scan<<<1, 1024, 0, stream>>>(deg, offsets, cur);
    k_scatter<<<gridE, TB, 0, stream>>>(ei, cur, csr_src);

    // layer 1
    k_gemm_attn<128, 8><<<gridG, TB, 0, stream>>>(x, W1, as1, ad1, h_buf, es1, ed1);
    k_agg1<<<N_NODES, TB, 0, stream>>>(h_buf, es1, ed1, offsets, csr_src, b1, out1);

    // layer 2 (h2 overwrites h1 buffer)
    k_gemm_attn<256, 1><<<gridG, TB, 0, stream>>>(out1, W2, as2, ad2, h_buf, es2, ed2);
    k_agg2<<<N_NODES, TB, 0, stream>>>(h_buf, es2, ed2, offsets, csr_src, b2, out);
}

// Round 2
// 640.662 us; speedup vs baseline: 2.4977x; 2.4977x over previous
//
#include <hip/hip_runtime.h>
#include <math.h>

#define N_NODES 50000
#define E_ORIG  500000
#define E_TOT   550000
#define CAPE    128   // per-node LDS edge cache; degree > CAPE falls back to recompute

typedef _Float16 half8 __attribute__((ext_vector_type(8)));
typedef float    v4f   __attribute__((ext_vector_type(4)));

// ------------------------------------------------------------------
// CSR build (group edges by destination node)
// ------------------------------------------------------------------
__global__ void k_zero(int* __restrict__ p, int n) {
    int i = blockIdx.x * blockDim.x + threadIdx.x;
    if (i < n) p[i] = 0;
}

__global__ void k_count(const int* __restrict__ ei, int* __restrict__ deg) {
    int e = blockIdx.x * blockDim.x + threadIdx.x;
    if (e >= E_TOT) return;
    int d = (e < E_ORIG) ? ei[E_ORIG + e] : (e - E_ORIG);
    atomicAdd(&deg[d], 1);
}

__global__ __launch_bounds__(1024) void k_scan(const int* __restrict__ deg,
                                               int* __restrict__ offsets,
                                               int* __restrict__ cur) {
    const int T = 1024, CH = 49;
    __shared__ int sums[T];
    int t = threadIdx.x;
    int beg = t * CH, end = min(beg + CH, N_NODES);
    int s = 0;
    for (int i = beg; i < end; i++) s += deg[i];
    sums[t] = s;
    __syncthreads();
    for (int offn = 1; offn < T; offn <<= 1) {
        int v = (t >= offn) ? sums[t - offn] : 0;
        __syncthreads();
        sums[t] += v;
        __syncthreads();
    }
    int run = (t == 0) ? 0 : sums[t - 1];
    for (int i = beg; i < end; i++) {
        offsets[i] = run;
        cur[i] = run;
        run += deg[i];
    }
    if (t == T - 1) offsets[N_NODES] = sums[T - 1];
}

__global__ void k_scatter(const int* __restrict__ ei, int* __restrict__ cur,
                          int* __restrict__ csr_src) {
    int e = blockIdx.x * blockDim.x + threadIdx.x;
    if (e >= E_TOT) return;
    int s, d;
    if (e < E_ORIG) { s = ei[e]; d = ei[E_ORIG + e]; }
    else            { s = e - E_ORIG; d = s; }
    int slot = atomicAdd(&cur[d], 1);
    csr_src[slot] = s;
}

// ------------------------------------------------------------------
// f32 -> f16 casts
// ------------------------------------------------------------------
__global__ void k_cast_x(const float* __restrict__ X, _Float16* __restrict__ Xh, int n4) {
    int i = blockIdx.x * blockDim.x + threadIdx.x;
    if (i >= n4) return;
    float4 v = ((const float4*)X)[i];
    _Float16* o = Xh + (size_t)i * 4;
    o[0] = (_Float16)v.x; o[1] = (_Float16)v.y; o[2] = (_Float16)v.z; o[3] = (_Float16)v.w;
}

// W[K][256] f32 -> Wt[256][K] f16
template <int K>
__global__ void k_transpose_w(const float* __restrict__ W, _Float16* __restrict__ Wt) {
    int i = blockIdx.x * blockDim.x + threadIdx.x;
    if (i >= K * 256) return;
    int k = i >> 8, c = i & 255;
    Wt[(size_t)c * K + k] = (_Float16)W[i];
}

// ------------------------------------------------------------------
// MFMA GEMM: H[N,256] = Xh[N,K] @ Wt[256,K]^T  (f16 in, f32 out)
// Block 256 thr = 4 waves; block tile 64 rows x 64 cols; wave 32x32.
// A frag: A[m=lane&15][k=quad*8+j]; B frag: B[k=quad*8+j][n=lane&15];
// C/D: col=lane&15, row=quad*4+reg.
// ------------------------------------------------------------------
template <int K>
__global__ __launch_bounds__(256) void k_mfma_gemm(const _Float16* __restrict__ A,
                                                   const _Float16* __restrict__ Bt,
                                                   float* __restrict__ H) {
    int t = threadIdx.x, w = t >> 6, lane = t & 63;
    int quad = lane >> 4, l16 = lane & 15;
    int row0 = blockIdx.x * 64 + (w & 1) * 32;
    int col0 = blockIdx.y * 64 + (w >> 1) * 32;

    v4f acc[2][2];
#pragma unroll
    for (int i = 0; i < 2; i++)
#pragma unroll
        for (int j = 0; j < 2; j++) acc[i][j] = (v4f){0.f, 0.f, 0.f, 0.f};

    int r0 = row0 + l16;       if (r0 >= N_NODES) r0 = N_NODES - 1;
    int r1 = row0 + 16 + l16;  if (r1 >= N_NODES) r1 = N_NODES - 1;
    const half8* a0 = (const half8*)(A + (size_t)r0 * K + quad * 8);
    const half8* a1 = (const half8*)(A + (size_t)r1 * K + quad * 8);
    const half8* b0 = (const half8*)(Bt + (size_t)(col0 + l16) * K + quad * 8);
    const half8* b1 = (const half8*)(Bt + (size_t)(col0 + 16 + l16) * K + quad * 8);

#pragma unroll
    for (int kc = 0; kc < K / 32; kc++) {
        half8 av0 = a0[kc * 4];
        half8 av1 = a1[kc * 4];
        half8 bv0 = b0[kc * 4];
        half8 bv1 = b1[kc * 4];
        acc[0][0] = __builtin_amdgcn_mfma_f32_16x16x32_f16(av0, bv0, acc[0][0], 0, 0, 0);
        acc[0][1] = __builtin_amdgcn_mfma_f32_16x16x32_f16(av0, bv1, acc[0][1], 0, 0, 0);
        acc[1][0] = __builtin_amdgcn_mfma_f32_16x16x32_f16(av1, bv0, acc[1][0], 0, 0, 0);
        acc[1][1] = __builtin_amdgcn_mfma_f32_16x16x32_f16(av1, bv1, acc[1][1], 0, 0, 0);
    }

#pragma unroll
    for (int rt = 0; rt < 2; rt++) {
#pragma unroll
        for (int reg = 0; reg < 4; reg++) {
            int row = row0 + rt * 16 + quad * 4 + reg;
            if (row < N_NODES) {
                H[(size_t)row * 256 + col0 + l16]      = acc[rt][0][reg];
                H[(size_t)row * 256 + col0 + 16 + l16] = acc[rt][1][reg];
            }
        }
    }
}

// ------------------------------------------------------------------
// Attention coefficients: es[n][h] = sum_c H[n][h*32+c]*a_src[h*32+c]
// One wave per node (4 nodes / 256-thr block).
// ------------------------------------------------------------------
template <int NH>
__global__ __launch_bounds__(256) void k_attn(const float* __restrict__ H,
                                              const float* __restrict__ a_s,
                                              const float* __restrict__ a_d,
                                              float* __restrict__ es,
                                              float* __restrict__ ed) {
    int t = threadIdx.x, w = t >> 6, lane = t & 63;
    int n = blockIdx.x * 4 + w;  // grid = 12500 exactly
    float4 h  = ((const float4*)(H + (size_t)n * 256))[lane];
    float4 av = ((const float4*)a_s)[lane];
    float4 dv = ((const float4*)a_d)[lane];
    float ps = h.x * av.x + h.y * av.y + h.z * av.z + h.w * av.w;
    float pd = h.x * dv.x + h.y * dv.y + h.z * dv.z + h.w * dv.w;
    if constexpr (NH == 8) {
#pragma unroll
        for (int mk = 1; mk < 8; mk <<= 1) {
            ps += __shfl_xor(ps, mk, 64);
            pd += __shfl_xor(pd, mk, 64);
        }
        if ((lane & 7) == 0) {
            es[(size_t)n * 8 + (lane >> 3)] = ps;
            ed[(size_t)n * 8 + (lane >> 3)] = pd;
        }
    } else {
#pragma unroll
        for (int mk = 1; mk < 64; mk <<= 1) {
            ps += __shfl_xor(ps, mk, 64);
            pd += __shfl_xor(pd, mk, 64);
        }
        if (lane == 0) { es[n] = ps; ed[n] = pd; }
    }
}

// ------------------------------------------------------------------
// Layer-1 aggregation: 8-head softmax over incoming edges, gather
// alpha-weighted source rows, +b1, ELU -> f16 (gemm2 input).
// ------------------------------------------------------------------
__global__ __launch_bounds__(256) void k_agg1(
    const float* __restrict__ H1, const float* __restrict__ es,
    const float* __restrict__ ed, const int* __restrict__ offsets,
    const int* __restrict__ csr_src, const float* __restrict__ b1,
    _Float16* __restrict__ out1) {
    int n = blockIdx.x;
    int t = threadIdx.x;
    int beg = offsets[n];
    int deg = offsets[n + 1] - beg;
    __shared__ int lsrc[CAPE];
    __shared__ float lalpha[CAPE * 8];
    __shared__ float sm[8], sd[8], sed[8];
    __shared__ float wred[4][8];

    if (t < 8) sed[t] = ed[(size_t)n * 8 + t];
    int ncap = deg < CAPE ? deg : CAPE;
    for (int i = t; i < ncap; i += 256) lsrc[i] = csr_src[beg + i];
    __syncthreads();

    int h = t & 7, slot = t >> 3;
    float mx = -1e30f;
    for (int i = slot; i < deg; i += 32) {
        int s = (i < CAPE) ? lsrc[i] : csr_src[beg + i];
        float l = es[(size_t)s * 8 + h] + sed[h];
        l = l > 0.f ? l : 0.2f * l;
        mx = fmaxf(mx, l);
    }
#pragma unroll
    for (int mk = 8; mk < 64; mk <<= 1) mx = fmaxf(mx, __shfl_xor(mx, mk, 64));
    if ((t & 63) < 8) wred[t >> 6][h] = mx;
    __syncthreads();
    if (t < 8)
        sm[t] = fmaxf(fmaxf(wred[0][t], wred[1][t]), fmaxf(wred[2][t], wred[3][t]));
    __syncthreads();

    float mh = sm[h];
    float sum = 0.f;
    for (int i = slot; i < deg; i += 32) {
        int s = (i < CAPE) ? lsrc[i] : csr_src[beg + i];
        float l = es[(size_t)s * 8 + h] + sed[h];
        l = l > 0.f ? l : 0.2f * l;
        sum += expf(l - mh);
    }
#pragma unroll
    for (int mk = 8; mk < 64; mk <<= 1) sum += __shfl_xor(sum, mk, 64);
    if ((t & 63) < 8) wred[t >> 6][h] = sum;
    __syncthreads();
    if (t < 8) sd[t] = wred[0][t] + wred[1][t] + wred[2][t] + wred[3][t] + 1e-16f;
    __syncthreads();

    for (int idx = t; idx < ncap * 8; idx += 256) {
        int i = idx >> 3, hh = idx & 7;
        int s = lsrc[i];
        float l = es[(size_t)s * 8 + hh] + sed[hh];
        l = l > 0.f ? l : 0.2f * l;
        lalpha[idx] = expf(l - sm[hh]) / sd[hh];
    }
    __syncthreads();

    int head = t >> 5;
    float accv = 0.f;
    for (int i = 0; i < deg; i++) {
        int s; float al;
        if (i < CAPE) { s = lsrc[i]; al = lalpha[i * 8 + head]; }
        else {
            s = csr_src[beg + i];
            float l = es[(size_t)s * 8 + head] + sed[head];
            l = l > 0.f ? l : 0.2f * l;
            al = expf(l - sm[head]) / sd[head];
        }
        accv += al * H1[(size_t)s * 256 + t];
    }
    float o = accv + b1[t];
    o = o > 0.f ? o : expf(o) - 1.f;  // ELU
    out1[(size_t)n * 256 + t] = (_Float16)o;
}

// ------------------------------------------------------------------
// Layer-2 aggregation: single head, +b2 -> d_out (f32)
// ------------------------------------------------------------------
__global__ __launch_bounds__(256) void k_agg2(
    const float* __restrict__ H2, const float* __restrict__ es,
    const float* __restrict__ ed, const int* __restrict__ offsets,
    const int* __restrict__ csr_src, const float* __restrict__ b2,
    float* __restrict__ out) {
    int n = blockIdx.x, t = threadIdx.x;
    int beg = offsets[n];
    int deg = offsets[n + 1] - beg;
    __shared__ int lsrc[CAPE];
    __shared__ float lalpha[CAPE];
    __shared__ float wredf[4];
    __shared__ float sstat[2];
    float edn = ed[n];
    int ncap = deg < CAPE ? deg : CAPE;
    for (int i = t; i < ncap; i += 256) lsrc[i] = csr_src[beg + i];
    __syncthreads();

    float mx = -1e30f;
    for (int i = t; i < deg; i += 256) {
        int s = (i < CAPE) ? lsrc[i] : csr_src[beg + i];
        float l = es[s] + edn; l = l > 0.f ? l : 0.2f * l;
        mx = fmaxf(mx, l);
    }
#pragma unroll
    for (int mk = 1; mk < 64; mk <<= 1) mx = fmaxf(mx, __shfl_xor(mx, mk, 64));
    if ((t & 63) == 0) wredf[t >> 6] = mx;
    __syncthreads();
    if (t == 0) sstat[0] = fmaxf(fmaxf(wredf[0], wredf[1]), fmaxf(wredf[2], wredf[3]));
    __syncthreads();
    float m0 = sstat[0];

    float sum = 0.f;
    for (int i = t; i < deg; i += 256) {
        int s = (i < CAPE) ? lsrc[i] : csr_src[beg + i];
        float l = es[s] + edn; l = l > 0.f ? l : 0.2f * l;
        sum += expf(l - m0);
    }
#pragma unroll
    for (int mk = 1; mk < 64; mk <<= 1) sum += __shfl_xor(sum, mk, 64);
    if ((t & 63) == 0) wredf[t >> 6] = sum;
    __syncthreads();
    if (t == 0) sstat[1] = wredf[0] + wredf[1] + wredf[2] + wredf[3] + 1e-16f;
    __syncthreads();
    float dn = sstat[1];

    for (int i = t; i < ncap; i += 256) {
        int s = lsrc[i];
        float l = es[s] + edn; l = l > 0.f ? l : 0.2f * l;
        lalpha[i] = expf(l - m0) / dn;
    }
    __syncthreads();

    float accv = 0.f;
    for (int i = 0; i < deg; i++) {
        int s; float al;
        if (i < CAPE) { s = lsrc[i]; al = lalpha[i]; }
        else {
            s = csr_src[beg + i];
            float l = es[s] + edn; l = l > 0.f ? l : 0.2f * l;
            al = expf(l - m0) / dn;
        }
        accv += al * H2[(size_t)s * 256 + t];
    }
    out[(size_t)n * 256 + t] = accv + b2[t];
}

// ------------------------------------------------------------------
extern "C" void kernel_launch(void* const* d_in, const int* in_sizes, int n_in,
                              void* d_out, int out_size, void* d_ws, size_t ws_size,
                              hipStream_t stream) {
    const float* x   = (const float*)d_in[0];
    const int*   ei  = (const int*)d_in[1];
    const float* W1  = (const float*)d_in[2];
    const float* as1 = (const float*)d_in[3];
    const float* ad1 = (const float*)d_in[4];
    const float* b1  = (const float*)d_in[5];
    const float* W2  = (const float*)d_in[6];
    const float* as2 = (const float*)d_in[7];
    const float* ad2 = (const float*)d_in[8];
    const float* b2  = (const float*)d_in[9];
    float* out = (float*)d_out;

    char* ws = (char*)d_ws;
    size_t off = 0;
    auto alloc = [&](size_t bytes) {
        void* p = ws + off;
        off = (off + bytes + 255) & ~(size_t)255;
        return p;
    };
    float*     h_buf   = (float*)alloc((size_t)N_NODES * 256 * 4);  // h1, then h2
    _Float16*  xh      = (_Float16*)alloc((size_t)N_NODES * 128 * 2);
    _Float16*  out1h   = (_Float16*)alloc((size_t)N_NODES * 256 * 2);
    _Float16*  w1t     = (_Float16*)alloc((size_t)128 * 256 * 2);
    _Float16*  w2t     = (_Float16*)alloc((size_t)256 * 256 * 2);
    float*     es1     = (float*)alloc((size_t)N_NODES * 8 * 4);
    float*     ed1     = (float*)alloc((size_t)N_NODES * 8 * 4);
    float*     es2     = (float*)alloc((size_t)N_NODES * 4);
    float*     ed2     = (float*)alloc((size_t)N_NODES * 4);
    int*       deg     = (int*)alloc((size_t)N_NODES * 4);
    int*       offsets = (int*)alloc((size_t)(N_NODES + 1) * 4);
    int*       cur     = (int*)alloc((size_t)N_NODES * 4);
    int*       csr_src = (int*)alloc((size_t)E_TOT * 4);

    const int TB = 256;
    int gridN = (N_NODES + TB - 1) / TB;
    int gridE = (E_TOT + TB - 1) / TB;

    // CSR build
    k_zero<<<gridN, TB, 0, stream>>>(deg, N_NODES);
    k_count<<<gridE, TB, 0, stream>>>(ei, deg);
    k_scan<<<1, 1024, 0, stream>>>(deg, offsets, cur);
    k_scatter<<<gridE, TB, 0, stream>>>(ei, cur, csr_src);

    // casts
    int n4x = N_NODES * 128 / 4;
    k_cast_x<<<(n4x + TB - 1) / TB, TB, 0, stream>>>(x, xh, n4x);
    k_transpose_w<128><<<(128 * 256 + TB - 1) / TB, TB, 0, stream>>>(W1, w1t);
    k_transpose_w<256><<<(256 * 256 + TB - 1) / TB, TB, 0, stream>>>(W2, w2t);

    dim3 gg1((N_NODES + 63) / 64, 4);

    // layer 1
    k_mfma_gemm<128><<<gg1, TB, 0, stream>>>(xh, w1t, h_buf);
    k_attn<8><<<N_NODES / 4, TB, 0, stream>>>(h_buf, as1, ad1, es1, ed1);
    k_agg1<<<N_NODES, TB, 0, stream>>>(h_buf, es1, ed1, offsets, csr_src, b1, out1h);

    // layer 2 (h2 overwrites h1 buffer)
    k_mfma_gemm<256><<<gg1, TB, 0, stream>>>(out1h, w2t, h_buf);
    k_attn<1><<<N_NODES / 4, TB, 0, stream>>>(h_buf, as2, ad2, es2, ed2);
    k_agg2<<<N_NODES, TB, 0, stream>>>(h_buf, es2, ed2, offsets, csr_src, b2, out);
}

// Round 3
// 528.851 us; speedup vs baseline: 3.0257x; 1.2114x over previous
//
#include <hip/hip_runtime.h>
#include <math.h>

#define N_NODES 50000
#define E_ORIG  500000
#define E_TOT   550000
#define CAPE    128   // per-node LDS edge cache; degree > CAPE falls back to recompute

typedef _Float16 half8 __attribute__((ext_vector_type(8)));
typedef float    v4f   __attribute__((ext_vector_type(4)));

// ------------------------------------------------------------------
// CSR build (group edges by destination node)
// ------------------------------------------------------------------
__global__ void k_zero(int* __restrict__ p, int n) {
    int i = blockIdx.x * blockDim.x + threadIdx.x;
    if (i < n) p[i] = 0;
}

__global__ void k_count(const int* __restrict__ ei, int* __restrict__ deg) {
    int e = blockIdx.x * blockDim.x + threadIdx.x;
    if (e >= E_TOT) return;
    int d = (e < E_ORIG) ? ei[E_ORIG + e] : (e - E_ORIG);
    atomicAdd(&deg[d], 1);
}

__global__ __launch_bounds__(1024) void k_scan(const int* __restrict__ deg,
                                               int* __restrict__ offsets,
                                               int* __restrict__ cur) {
    const int T = 1024, CH = 49;
    __shared__ int sums[T];
    int t = threadIdx.x;
    int beg = t * CH, end = min(beg + CH, N_NODES);
    int s = 0;
    for (int i = beg; i < end; i++) s += deg[i];
    sums[t] = s;
    __syncthreads();
    for (int offn = 1; offn < T; offn <<= 1) {
        int v = (t >= offn) ? sums[t - offn] : 0;
        __syncthreads();
        sums[t] += v;
        __syncthreads();
    }
    int run = (t == 0) ? 0 : sums[t - 1];
    for (int i = beg; i < end; i++) {
        offsets[i] = run;
        cur[i] = run;
        run += deg[i];
    }
    if (t == T - 1) offsets[N_NODES] = sums[T - 1];
}

__global__ void k_scatter(const int* __restrict__ ei, int* __restrict__ cur,
                          int* __restrict__ csr_src) {
    int e = blockIdx.x * blockDim.x + threadIdx.x;
    if (e >= E_TOT) return;
    int s, d;
    if (e < E_ORIG) { s = ei[e]; d = ei[E_ORIG + e]; }
    else            { s = e - E_ORIG; d = s; }
    int slot = atomicAdd(&cur[d], 1);
    csr_src[slot] = s;
}

// ------------------------------------------------------------------
// f32 -> f16 casts
// ------------------------------------------------------------------
__global__ void k_cast_x(const float* __restrict__ X, _Float16* __restrict__ Xh, int n4) {
    int i = blockIdx.x * blockDim.x + threadIdx.x;
    if (i >= n4) return;
    float4 v = ((const float4*)X)[i];
    _Float16* o = Xh + (size_t)i * 4;
    o[0] = (_Float16)v.x; o[1] = (_Float16)v.y; o[2] = (_Float16)v.z; o[3] = (_Float16)v.w;
}

// W[K][256] f32 -> Wt[256][K] f16
template <int K>
__global__ void k_transpose_w(const float* __restrict__ W, _Float16* __restrict__ Wt) {
    int i = blockIdx.x * blockDim.x + threadIdx.x;
    if (i >= K * 256) return;
    int k = i >> 8, c = i & 255;
    Wt[(size_t)c * K + k] = (_Float16)W[i];
}

// ------------------------------------------------------------------
// MFMA GEMM + fused attention coefficients.
// H[N,256] = A[N,K] @ Bt[256,K]^T  (f16 in, f32 acc, f16 out)
// es/ed[n][h] = sum_c H[n][h*C+c] * a_{src,dst}[h*C+c]
// Block 256 thr = 4 waves; block tile 64 rows x 256 cols.
// Wave (rh = w&1, ch = w>>1): rows row0+rh*32 .. +32, cols ch*128 .. +128
// A frag: A[m=lane&15][k=quad*8+j]; B frag: B[k=quad*8+j][n=lane&15];
// C/D: col=lane&15, row=quad*4+reg.
// NH=8: each wave's 128 cols = heads ch*4..ch*4+3 (2 col-tiles per head),
//       quad-local (16-lane) shfl reduce, direct store.
// NH=1: per-wave partial over 128 cols -> LDS combine across ch.
// ------------------------------------------------------------------
template <int K, int NH>
__global__ __launch_bounds__(256) void k_mfma_gemm(
    const _Float16* __restrict__ A, const _Float16* __restrict__ Bt,
    const float* __restrict__ a_s, const float* __restrict__ a_d,
    _Float16* __restrict__ H, float* __restrict__ es, float* __restrict__ ed) {
    int t = threadIdx.x, w = t >> 6, lane = t & 63;
    int quad = lane >> 4, l16 = lane & 15;
    int rh = w & 1, ch = w >> 1;
    int row0 = blockIdx.x * 64 + rh * 32;
    int colbase = ch * 128;

    v4f acc[2][8];
#pragma unroll
    for (int i = 0; i < 2; i++)
#pragma unroll
        for (int j = 0; j < 8; j++) acc[i][j] = (v4f){0.f, 0.f, 0.f, 0.f};

    int r0 = row0 + l16;      if (r0 >= N_NODES) r0 = N_NODES - 1;
    int r1 = row0 + 16 + l16; if (r1 >= N_NODES) r1 = N_NODES - 1;
    const half8* a0 = (const half8*)(A + (size_t)r0 * K + quad * 8);
    const half8* a1 = (const half8*)(A + (size_t)r1 * K + quad * 8);
    const half8* bp[8];
#pragma unroll
    for (int ct = 0; ct < 8; ct++)
        bp[ct] = (const half8*)(Bt + (size_t)(colbase + ct * 16 + l16) * K + quad * 8);

#pragma unroll
    for (int kc = 0; kc < K / 32; kc++) {
        half8 av0 = a0[kc * 4];
        half8 av1 = a1[kc * 4];
#pragma unroll
        for (int ct = 0; ct < 8; ct++) {
            half8 bv = bp[ct][kc * 4];
            acc[0][ct] = __builtin_amdgcn_mfma_f32_16x16x32_f16(av0, bv, acc[0][ct], 0, 0, 0);
            acc[1][ct] = __builtin_amdgcn_mfma_f32_16x16x32_f16(av1, bv, acc[1][ct], 0, 0, 0);
        }
    }

    // store H (f16)
#pragma unroll
    for (int rt = 0; rt < 2; rt++) {
#pragma unroll
        for (int reg = 0; reg < 4; reg++) {
            int row = row0 + rt * 16 + quad * 4 + reg;
            if (row < N_NODES) {
#pragma unroll
                for (int ct = 0; ct < 8; ct++)
                    H[(size_t)row * 256 + colbase + ct * 16 + l16] = (_Float16)acc[rt][ct][reg];
            }
        }
    }

    // attention coefficients
    float asv[8], adv[8];
#pragma unroll
    for (int ct = 0; ct < 8; ct++) {
        asv[ct] = a_s[colbase + ct * 16 + l16];
        adv[ct] = a_d[colbase + ct * 16 + l16];
    }

    if constexpr (NH == 8) {
#pragma unroll
        for (int rt = 0; rt < 2; rt++) {
#pragma unroll
            for (int hp = 0; hp < 4; hp++) {
#pragma unroll
                for (int reg = 0; reg < 4; reg++) {
                    float ps = acc[rt][2 * hp][reg] * asv[2 * hp] +
                               acc[rt][2 * hp + 1][reg] * asv[2 * hp + 1];
                    float pd = acc[rt][2 * hp][reg] * adv[2 * hp] +
                               acc[rt][2 * hp + 1][reg] * adv[2 * hp + 1];
#pragma unroll
                    for (int mk = 1; mk < 16; mk <<= 1) {
                        ps += __shfl_xor(ps, mk, 64);
                        pd += __shfl_xor(pd, mk, 64);
                    }
                    if (l16 == 0) {
                        int row = row0 + rt * 16 + quad * 4 + reg;
                        if (row < N_NODES) {
                            int head = ch * 4 + hp;
                            es[(size_t)row * 8 + head] = ps;
                            ed[(size_t)row * 8 + head] = pd;
                        }
                    }
                }
            }
        }
    } else {
        __shared__ float esp[2][64], edp[2][64];
#pragma unroll
        for (int rt = 0; rt < 2; rt++) {
#pragma unroll
            for (int reg = 0; reg < 4; reg++) {
                float ps = 0.f, pd = 0.f;
#pragma unroll
                for (int ct = 0; ct < 8; ct++) {
                    ps += acc[rt][ct][reg] * asv[ct];
                    pd += acc[rt][ct][reg] * adv[ct];
                }
#pragma unroll
                for (int mk = 1; mk < 16; mk <<= 1) {
                    ps += __shfl_xor(ps, mk, 64);
                    pd += __shfl_xor(pd, mk, 64);
                }
                if (l16 == 0) {
                    int lrow = rh * 32 + rt * 16 + quad * 4 + reg;
                    esp[ch][lrow] = ps;
                    edp[ch][lrow] = pd;
                }
            }
        }
        __syncthreads();
        if (t < 64) {
            int row = blockIdx.x * 64 + t;
            if (row < N_NODES) {
                es[row] = esp[0][t] + esp[1][t];
                ed[row] = edp[0][t] + edp[1][t];
            }
        }
    }
}

// ------------------------------------------------------------------
// Layer-1 aggregation: 8-head softmax (no max pass; logits are O(1)),
// exp cached in LDS, denominator factored out of the gather.
// Gathers f16 H rows. Output f16 (gemm2 input), +b1, ELU.
// ------------------------------------------------------------------
__global__ __launch_bounds__(256) void k_agg1(
    const _Float16* __restrict__ H1, const float* __restrict__ es,
    const float* __restrict__ ed, const int* __restrict__ offsets,
    const int* __restrict__ csr_src, const float* __restrict__ b1,
    _Float16* __restrict__ out1) {
    int n = blockIdx.x, t = threadIdx.x;
    int beg = offsets[n];
    int deg = offsets[n + 1] - beg;
    int ncap = deg < CAPE ? deg : CAPE;
    __shared__ int lsrc[CAPE];
    __shared__ float le[CAPE * 8];
    __shared__ float sed[8], sdn[8];
    __shared__ float wred[4][8];

    if (t < 8) sed[t] = ed[(size_t)n * 8 + t];
    for (int i = t; i < ncap; i += 256) lsrc[i] = csr_src[beg + i];
    __syncthreads();

    int h = t & 7, slot = t >> 3;  // 32 slots x 8 heads
    float sum = 0.f;
    for (int i = slot; i < ncap; i += 32) {
        int s = lsrc[i];
        float l = es[(size_t)s * 8 + h] + sed[h];
        l = l > 0.f ? l : 0.2f * l;
        float e = __expf(l);
        le[i * 8 + h] = e;
        sum += e;
    }
    for (int i = CAPE + slot; i < deg; i += 32) {  // overflow fallback (rare)
        int s = csr_src[beg + i];
        float l = es[(size_t)s * 8 + h] + sed[h];
        l = l > 0.f ? l : 0.2f * l;
        sum += __expf(l);
    }
#pragma unroll
    for (int mk = 8; mk < 64; mk <<= 1) sum += __shfl_xor(sum, mk, 64);
    if ((t & 63) < 8) wred[t >> 6][h] = sum;
    __syncthreads();
    if (t < 8) sdn[t] = wred[0][t] + wred[1][t] + wred[2][t] + wred[3][t] + 1e-16f;
    __syncthreads();

    int head = t >> 5;
    float acc = 0.f;
    for (int i = 0; i < ncap; i++) {
        int s = lsrc[i];
        acc += le[i * 8 + head] * (float)H1[(size_t)s * 256 + t];
    }
    for (int i = CAPE; i < deg; i++) {
        int s = csr_src[beg + i];
        float l = es[(size_t)s * 8 + head] + sed[head];
        l = l > 0.f ? l : 0.2f * l;
        acc += __expf(l) * (float)H1[(size_t)s * 256 + t];
    }
    float o = acc / sdn[head] + b1[t];
    o = o > 0.f ? o : __expf(o) - 1.f;  // ELU
    out1[(size_t)n * 256 + t] = (_Float16)o;
}

// ------------------------------------------------------------------
// Layer-2 aggregation: single head, +b2 -> d_out (f32)
// ------------------------------------------------------------------
__global__ __launch_bounds__(256) void k_agg2(
    const _Float16* __restrict__ H2, const float* __restrict__ es,
    const float* __restrict__ ed, const int* __restrict__ offsets,
    const int* __restrict__ csr_src, const float* __restrict__ b2,
    float* __restrict__ out) {
    int n = blockIdx.x, t = threadIdx.x;
    int beg = offsets[n];
    int deg = offsets[n + 1] - beg;
    int ncap = deg < CAPE ? deg : CAPE;
    __shared__ int lsrc[CAPE];
    __shared__ float le[CAPE];
    __shared__ float wredf[4];
    __shared__ float sdn1;
    float edn = ed[n];
    for (int i = t; i < ncap; i += 256) lsrc[i] = csr_src[beg + i];
    __syncthreads();

    float sum = 0.f;
    for (int i = t; i < ncap; i += 256) {
        int s = lsrc[i];
        float l = es[s] + edn; l = l > 0.f ? l : 0.2f * l;
        float e = __expf(l);
        le[i] = e;
        sum += e;
    }
    for (int i = CAPE + t; i < deg; i += 256) {
        int s = csr_src[beg + i];
        float l = es[s] + edn; l = l > 0.f ? l : 0.2f * l;
        sum += __expf(l);
    }
#pragma unroll
    for (int mk = 1; mk < 64; mk <<= 1) sum += __shfl_xor(sum, mk, 64);
    if ((t & 63) == 0) wredf[t >> 6] = sum;
    __syncthreads();
    if (t == 0) sdn1 = wredf[0] + wredf[1] + wredf[2] + wredf[3] + 1e-16f;
    __syncthreads();
    float dn = sdn1;

    float acc = 0.f;
    for (int i = 0; i < ncap; i++) {
        int s = lsrc[i];
        acc += le[i] * (float)H2[(size_t)s * 256 + t];
    }
    for (int i = CAPE; i < deg; i++) {
        int s = csr_src[beg + i];
        float l = es[s] + edn; l = l > 0.f ? l : 0.2f * l;
        acc += __expf(l) * (float)H2[(size_t)s * 256 + t];
    }
    out[(size_t)n * 256 + t] = acc / dn + b2[t];
}

// ------------------------------------------------------------------
extern "C" void kernel_launch(void* const* d_in, const int* in_sizes, int n_in,
                              void* d_out, int out_size, void* d_ws, size_t ws_size,
                              hipStream_t stream) {
    const float* x   = (const float*)d_in[0];
    const int*   ei  = (const int*)d_in[1];
    const float* W1  = (const float*)d_in[2];
    const float* as1 = (const float*)d_in[3];
    const float* ad1 = (const float*)d_in[4];
    const float* b1  = (const float*)d_in[5];
    const float* W2  = (const float*)d_in[6];
    const float* as2 = (const float*)d_in[7];
    const float* ad2 = (const float*)d_in[8];
    const float* b2  = (const float*)d_in[9];
    float* out = (float*)d_out;

    char* ws = (char*)d_ws;
    size_t off = 0;
    auto alloc = [&](size_t bytes) {
        void* p = ws + off;
        off = (off + bytes + 255) & ~(size_t)255;
        return p;
    };
    _Float16* h1h     = (_Float16*)alloc((size_t)N_NODES * 256 * 2);
    _Float16* h2h     = (_Float16*)alloc((size_t)N_NODES * 256 * 2);
    _Float16* out1h   = (_Float16*)alloc((size_t)N_NODES * 256 * 2);
    _Float16* xh      = (_Float16*)alloc((size_t)N_NODES * 128 * 2);
    _Float16* w1t     = (_Float16*)alloc((size_t)128 * 256 * 2);
    _Float16* w2t     = (_Float16*)alloc((size_t)256 * 256 * 2);
    float*    es1     = (float*)alloc((size_t)N_NODES * 8 * 4);
    float*    ed1     = (float*)alloc((size_t)N_NODES * 8 * 4);
    float*    es2     = (float*)alloc((size_t)N_NODES * 4);
    float*    ed2     = (float*)alloc((size_t)N_NODES * 4);
    int*      deg     = (int*)alloc((size_t)N_NODES * 4);
    int*      offsets = (int*)alloc((size_t)(N_NODES + 1) * 4);
    int*      cur     = (int*)alloc((size_t)N_NODES * 4);
    int*      csr_src = (int*)alloc((size_t)E_TOT * 4);

    const int TB = 256;
    int gridN = (N_NODES + TB - 1) / TB;
    int gridE = (E_TOT + TB - 1) / TB;
    int gridG = (N_NODES + 63) / 64;

    // CSR build
    k_zero<<<gridN, TB, 0, stream>>>(deg, N_NODES);
    k_count<<<gridE, TB, 0, stream>>>(ei, deg);
    k_scan<<<1, 1024, 0, stream>>>(deg, offsets, cur);
    k_scatter<<<gridE, TB, 0, stream>>>(ei, cur, csr_src);

    // casts
    int n4x = N_NODES * 128 / 4;
    k_cast_x<<<(n4x + TB - 1) / TB, TB, 0, stream>>>(x, xh, n4x);
    k_transpose_w<128><<<(128 * 256 + TB - 1) / TB, TB, 0, stream>>>(W1, w1t);
    k_transpose_w<256><<<(256 * 256 + TB - 1) / TB, TB, 0, stream>>>(W2, w2t);

    // layer 1
    k_mfma_gemm<128, 8><<<gridG, TB, 0, stream>>>(xh, w1t, as1, ad1, h1h, es1, ed1);
    k_agg1<<<N_NODES, TB, 0, stream>>>(h1h, es1, ed1, offsets, csr_src, b1, out1h);

    // layer 2
    k_mfma_gemm<256, 1><<<gridG, TB, 0, stream>>>(out1h, w2t, as2, ad2, h2h, es2, ed2);
    k_agg2<<<N_NODES, TB, 0, stream>>>(h2h, es2, ed2, offsets, csr_src, b2, out);
}

// Round 4
// 426.545 us; speedup vs baseline: 3.7514x; 1.2399x over previous
//
#include <hip/hip_runtime.h>
#include <math.h>

#define N_NODES 50000
#define E_ORIG  500000
#define E_TOT   550000
#define CAPE    128   // per-node LDS edge cache; degree > CAPE falls back to recompute
#define NB      196   // scan blocks: 196*256 = 50176 >= N_NODES

typedef _Float16 half8 __attribute__((ext_vector_type(8)));
typedef float    v4f   __attribute__((ext_vector_type(4)));

// ------------------------------------------------------------------
// CSR build (group edges by destination node)
// ------------------------------------------------------------------
__global__ void k_zero(int* __restrict__ p, int n) {
    int i = blockIdx.x * blockDim.x + threadIdx.x;
    if (i < n) p[i] = 0;
}

__global__ void k_count(const int* __restrict__ ei, int* __restrict__ deg) {
    int e = blockIdx.x * blockDim.x + threadIdx.x;
    if (e >= E_TOT) return;
    int d = (e < E_ORIG) ? ei[E_ORIG + e] : (e - E_ORIG);
    atomicAdd(&deg[d], 1);
}

// --- 3-phase multi-block exclusive scan of deg[N_NODES] ---
__global__ __launch_bounds__(256) void k_blocksum(const int* __restrict__ deg,
                                                  int* __restrict__ bsum) {
    int t = threadIdx.x;
    int i = blockIdx.x * 256 + t;
    int v = (i < N_NODES) ? deg[i] : 0;
#pragma unroll
    for (int mk = 1; mk < 64; mk <<= 1) v += __shfl_xor(v, mk, 64);
    __shared__ int ws[4];
    if ((t & 63) == 0) ws[t >> 6] = v;
    __syncthreads();
    if (t == 0) bsum[blockIdx.x] = ws[0] + ws[1] + ws[2] + ws[3];
}

__global__ __launch_bounds__(256) void k_scanbsum(const int* __restrict__ bsum,
                                                  int* __restrict__ boff) {
    __shared__ int s[256];
    int t = threadIdx.x;
    int v = (t < NB) ? bsum[t] : 0;
    s[t] = v;
    __syncthreads();
    for (int o = 1; o < 256; o <<= 1) {
        int x = (t >= o) ? s[t - o] : 0;
        __syncthreads();
        s[t] += x;
        __syncthreads();
    }
    if (t <= NB) boff[t] = (t == 0) ? 0 : s[t - 1];
}

__global__ __launch_bounds__(256) void k_offsets(const int* __restrict__ deg,
                                                 const int* __restrict__ boff,
                                                 int* __restrict__ offsets,
                                                 int* __restrict__ cur) {
    __shared__ int s[256];
    int t = threadIdx.x;
    int i = blockIdx.x * 256 + t;
    int v = (i < N_NODES) ? deg[i] : 0;
    s[t] = v;
    __syncthreads();
    for (int o = 1; o < 256; o <<= 1) {
        int x = (t >= o) ? s[t - o] : 0;
        __syncthreads();
        s[t] += x;
        __syncthreads();
    }
    int off = boff[blockIdx.x] + s[t] - v;  // exclusive
    if (i <= N_NODES) {
        offsets[i] = off;
        if (i < N_NODES) cur[i] = off;
    }
}

__global__ void k_scatter(const int* __restrict__ ei, int* __restrict__ cur,
                          int* __restrict__ csr_src) {
    int e = blockIdx.x * blockDim.x + threadIdx.x;
    if (e >= E_TOT) return;
    int s, d;
    if (e < E_ORIG) { s = ei[e]; d = ei[E_ORIG + e]; }
    else            { s = e - E_ORIG; d = s; }
    int slot = atomicAdd(&cur[d], 1);
    csr_src[slot] = s;
}

// ------------------------------------------------------------------
// f32 -> f16 casts
// ------------------------------------------------------------------
__global__ void k_cast_x(const float* __restrict__ X, _Float16* __restrict__ Xh, int n4) {
    int i = blockIdx.x * blockDim.x + threadIdx.x;
    if (i >= n4) return;
    float4 v = ((const float4*)X)[i];
    _Float16* o = Xh + (size_t)i * 4;
    o[0] = (_Float16)v.x; o[1] = (_Float16)v.y; o[2] = (_Float16)v.z; o[3] = (_Float16)v.w;
}

// W[K][256] f32 -> Wt[256][K] f16
template <int K>
__global__ void k_transpose_w(const float* __restrict__ W, _Float16* __restrict__ Wt) {
    int i = blockIdx.x * blockDim.x + threadIdx.x;
    if (i >= K * 256) return;
    int k = i >> 8, c = i & 255;
    Wt[(size_t)c * K + k] = (_Float16)W[i];
}

// ------------------------------------------------------------------
// MFMA GEMM + fused attention coefficients.  (unchanged from R3)
// ------------------------------------------------------------------
template <int K, int NH>
__global__ __launch_bounds__(256) void k_mfma_gemm(
    const _Float16* __restrict__ A, const _Float16* __restrict__ Bt,
    const float* __restrict__ a_s, const float* __restrict__ a_d,
    _Float16* __restrict__ H, float* __restrict__ es, float* __restrict__ ed) {
    int t = threadIdx.x, w = t >> 6, lane = t & 63;
    int quad = lane >> 4, l16 = lane & 15;
    int rh = w & 1, ch = w >> 1;
    int row0 = blockIdx.x * 64 + rh * 32;
    int colbase = ch * 128;

    v4f acc[2][8];
#pragma unroll
    for (int i = 0; i < 2; i++)
#pragma unroll
        for (int j = 0; j < 8; j++) acc[i][j] = (v4f){0.f, 0.f, 0.f, 0.f};

    int r0 = row0 + l16;      if (r0 >= N_NODES) r0 = N_NODES - 1;
    int r1 = row0 + 16 + l16; if (r1 >= N_NODES) r1 = N_NODES - 1;
    const half8* a0 = (const half8*)(A + (size_t)r0 * K + quad * 8);
    const half8* a1 = (const half8*)(A + (size_t)r1 * K + quad * 8);
    const half8* bp[8];
#pragma unroll
    for (int ct = 0; ct < 8; ct++)
        bp[ct] = (const half8*)(Bt + (size_t)(colbase + ct * 16 + l16) * K + quad * 8);

#pragma unroll
    for (int kc = 0; kc < K / 32; kc++) {
        half8 av0 = a0[kc * 4];
        half8 av1 = a1[kc * 4];
#pragma unroll
        for (int ct = 0; ct < 8; ct++) {
            half8 bv = bp[ct][kc * 4];
            acc[0][ct] = __builtin_amdgcn_mfma_f32_16x16x32_f16(av0, bv, acc[0][ct], 0, 0, 0);
            acc[1][ct] = __builtin_amdgcn_mfma_f32_16x16x32_f16(av1, bv, acc[1][ct], 0, 0, 0);
        }
    }

#pragma unroll
    for (int rt = 0; rt < 2; rt++) {
#pragma unroll
        for (int reg = 0; reg < 4; reg++) {
            int row = row0 + rt * 16 + quad * 4 + reg;
            if (row < N_NODES) {
#pragma unroll
                for (int ct = 0; ct < 8; ct++)
                    H[(size_t)row * 256 + colbase + ct * 16 + l16] = (_Float16)acc[rt][ct][reg];
            }
        }
    }

    float asv[8], adv[8];
#pragma unroll
    for (int ct = 0; ct < 8; ct++) {
        asv[ct] = a_s[colbase + ct * 16 + l16];
        adv[ct] = a_d[colbase + ct * 16 + l16];
    }

    if constexpr (NH == 8) {
#pragma unroll
        for (int rt = 0; rt < 2; rt++) {
#pragma unroll
            for (int hp = 0; hp < 4; hp++) {
#pragma unroll
                for (int reg = 0; reg < 4; reg++) {
                    float ps = acc[rt][2 * hp][reg] * asv[2 * hp] +
                               acc[rt][2 * hp + 1][reg] * asv[2 * hp + 1];
                    float pd = acc[rt][2 * hp][reg] * adv[2 * hp] +
                               acc[rt][2 * hp + 1][reg] * adv[2 * hp + 1];
#pragma unroll
                    for (int mk = 1; mk < 16; mk <<= 1) {
                        ps += __shfl_xor(ps, mk, 64);
                        pd += __shfl_xor(pd, mk, 64);
                    }
                    if (l16 == 0) {
                        int row = row0 + rt * 16 + quad * 4 + reg;
                        if (row < N_NODES) {
                            int head = ch * 4 + hp;
                            es[(size_t)row * 8 + head] = ps;
                            ed[(size_t)row * 8 + head] = pd;
                        }
                    }
                }
            }
        }
    } else {
        __shared__ float esp[2][64], edp[2][64];
#pragma unroll
        for (int rt = 0; rt < 2; rt++) {
#pragma unroll
            for (int reg = 0; reg < 4; reg++) {
                float ps = 0.f, pd = 0.f;
#pragma unroll
                for (int ct = 0; ct < 8; ct++) {
                    ps += acc[rt][ct][reg] * asv[ct];
                    pd += acc[rt][ct][reg] * adv[ct];
                }
#pragma unroll
                for (int mk = 1; mk < 16; mk <<= 1) {
                    ps += __shfl_xor(ps, mk, 64);
                    pd += __shfl_xor(pd, mk, 64);
                }
                if (l16 == 0) {
                    int lrow = rh * 32 + rt * 16 + quad * 4 + reg;
                    esp[ch][lrow] = ps;
                    edp[ch][lrow] = pd;
                }
            }
        }
        __syncthreads();
        if (t < 64) {
            int row = blockIdx.x * 64 + t;
            if (row < N_NODES) {
                es[row] = esp[0][t] + esp[1][t];
                ed[row] = edp[0][t] + edp[1][t];
            }
        }
    }
}

// ------------------------------------------------------------------
// Layer-1 aggregation (unchanged from R3)
// ------------------------------------------------------------------
__global__ __launch_bounds__(256) void k_agg1(
    const _Float16* __restrict__ H1, const float* __restrict__ es,
    const float* __restrict__ ed, const int* __restrict__ offsets,
    const int* __restrict__ csr_src, const float* __restrict__ b1,
    _Float16* __restrict__ out1) {
    int n = blockIdx.x, t = threadIdx.x;
    int beg = offsets[n];
    int deg = offsets[n + 1] - beg;
    int ncap = deg < CAPE ? deg : CAPE;
    __shared__ int lsrc[CAPE];
    __shared__ float le[CAPE * 8];
    __shared__ float sed[8], sdn[8];
    __shared__ float wred[4][8];

    if (t < 8) sed[t] = ed[(size_t)n * 8 + t];
    for (int i = t; i < ncap; i += 256) lsrc[i] = csr_src[beg + i];
    __syncthreads();

    int h = t & 7, slot = t >> 3;
    float sum = 0.f;
    for (int i = slot; i < ncap; i += 32) {
        int s = lsrc[i];
        float l = es[(size_t)s * 8 + h] + sed[h];
        l = l > 0.f ? l : 0.2f * l;
        float e = __expf(l);
        le[i * 8 + h] = e;
        sum += e;
    }
    for (int i = CAPE + slot; i < deg; i += 32) {
        int s = csr_src[beg + i];
        float l = es[(size_t)s * 8 + h] + sed[h];
        l = l > 0.f ? l : 0.2f * l;
        sum += __expf(l);
    }
#pragma unroll
    for (int mk = 8; mk < 64; mk <<= 1) sum += __shfl_xor(sum, mk, 64);
    if ((t & 63) < 8) wred[t >> 6][h] = sum;
    __syncthreads();
    if (t < 8) sdn[t] = wred[0][t] + wred[1][t] + wred[2][t] + wred[3][t] + 1e-16f;
    __syncthreads();

    int head = t >> 5;
    float acc = 0.f;
    for (int i = 0; i < ncap; i++) {
        int s = lsrc[i];
        acc += le[i * 8 + head] * (float)H1[(size_t)s * 256 + t];
    }
    for (int i = CAPE; i < deg; i++) {
        int s = csr_src[beg + i];
        float l = es[(size_t)s * 8 + head] + sed[head];
        l = l > 0.f ? l : 0.2f * l;
        acc += __expf(l) * (float)H1[(size_t)s * 256 + t];
    }
    float o = acc / sdn[head] + b1[t];
    o = o > 0.f ? o : __expf(o) - 1.f;  // ELU
    out1[(size_t)n * 256 + t] = (_Float16)o;
}

// ------------------------------------------------------------------
// Layer-2 aggregation (unchanged from R3)
// ------------------------------------------------------------------
__global__ __launch_bounds__(256) void k_agg2(
    const _Float16* __restrict__ H2, const float* __restrict__ es,
    const float* __restrict__ ed, const int* __restrict__ offsets,
    const int* __restrict__ csr_src, const float* __restrict__ b2,
    float* __restrict__ out) {
    int n = blockIdx.x, t = threadIdx.x;
    int beg = offsets[n];
    int deg = offsets[n + 1] - beg;
    int ncap = deg < CAPE ? deg : CAPE;
    __shared__ int lsrc[CAPE];
    __shared__ float le[CAPE];
    __shared__ float wredf[4];
    __shared__ float sdn1;
    float edn = ed[n];
    for (int i = t; i < ncap; i += 256) lsrc[i] = csr_src[beg + i];
    __syncthreads();

    float sum = 0.f;
    for (int i = t; i < ncap; i += 256) {
        int s = lsrc[i];
        float l = es[s] + edn; l = l > 0.f ? l : 0.2f * l;
        float e = __expf(l);
        le[i] = e;
        sum += e;
    }
    for (int i = CAPE + t; i < deg; i += 256) {
        int s = csr_src[beg + i];
        float l = es[s] + edn; l = l > 0.f ? l : 0.2f * l;
        sum += __expf(l);
    }
#pragma unroll
    for (int mk = 1; mk < 64; mk <<= 1) sum += __shfl_xor(sum, mk, 64);
    if ((t & 63) == 0) wredf[t >> 6] = sum;
    __syncthreads();
    if (t == 0) sdn1 = wredf[0] + wredf[1] + wredf[2] + wredf[3] + 1e-16f;
    __syncthreads();
    float dn = sdn1;

    float acc = 0.f;
    for (int i = 0; i < ncap; i++) {
        int s = lsrc[i];
        acc += le[i] * (float)H2[(size_t)s * 256 + t];
    }
    for (int i = CAPE; i < deg; i++) {
        int s = csr_src[beg + i];
        float l = es[s] + edn; l = l > 0.f ? l : 0.2f * l;
        acc += __expf(l) * (float)H2[(size_t)s * 256 + t];
    }
    out[(size_t)n * 256 + t] = acc / dn + b2[t];
}

// ------------------------------------------------------------------
extern "C" void kernel_launch(void* const* d_in, const int* in_sizes, int n_in,
                              void* d_out, int out_size, void* d_ws, size_t ws_size,
                              hipStream_t stream) {
    const float* x   = (const float*)d_in[0];
    const int*   ei  = (const int*)d_in[1];
    const float* W1  = (const float*)d_in[2];
    const float* as1 = (const float*)d_in[3];
    const float* ad1 = (const float*)d_in[4];
    const float* b1  = (const float*)d_in[5];
    const float* W2  = (const float*)d_in[6];
    const float* as2 = (const float*)d_in[7];
    const float* ad2 = (const float*)d_in[8];
    const float* b2  = (const float*)d_in[9];
    float* out = (float*)d_out;

    char* ws = (char*)d_ws;
    size_t off = 0;
    auto alloc = [&](size_t bytes) {
        void* p = ws + off;
        off = (off + bytes + 255) & ~(size_t)255;
        return p;
    };
    _Float16* h1h     = (_Float16*)alloc((size_t)N_NODES * 256 * 2);
    _Float16* h2h     = (_Float16*)alloc((size_t)N_NODES * 256 * 2);
    _Float16* out1h   = (_Float16*)alloc((size_t)N_NODES * 256 * 2);
    _Float16* xh      = (_Float16*)alloc((size_t)N_NODES * 128 * 2);
    _Float16* w1t     = (_Float16*)alloc((size_t)128 * 256 * 2);
    _Float16* w2t     = (_Float16*)alloc((size_t)256 * 256 * 2);
    float*    es1     = (float*)alloc((size_t)N_NODES * 8 * 4);
    float*    ed1     = (float*)alloc((size_t)N_NODES * 8 * 4);
    float*    es2     = (float*)alloc((size_t)N_NODES * 4);
    float*    ed2     = (float*)alloc((size_t)N_NODES * 4);
    int*      deg     = (int*)alloc((size_t)N_NODES * 4);
    int*      offsets = (int*)alloc((size_t)(N_NODES + 1) * 4);
    int*      cur     = (int*)alloc((size_t)N_NODES * 4);
    int*      csr_src = (int*)alloc((size_t)E_TOT * 4);
    int*      bsum    = (int*)alloc((size_t)NB * 4);
    int*      boff    = (int*)alloc((size_t)(NB + 1) * 4);

    const int TB = 256;
    int gridN = (N_NODES + TB - 1) / TB;
    int gridE = (E_TOT + TB - 1) / TB;
    int gridG = (N_NODES + 63) / 64;

    // CSR build
    k_zero<<<gridN, TB, 0, stream>>>(deg, N_NODES);
    k_count<<<gridE, TB, 0, stream>>>(ei, deg);
    k_blocksum<<<NB, TB, 0, stream>>>(deg, bsum);
    k_scanbsum<<<1, TB, 0, stream>>>(bsum, boff);
    k_offsets<<<NB, TB, 0, stream>>>(deg, boff, offsets, cur);
    k_scatter<<<gridE, TB, 0, stream>>>(ei, cur, csr_src);

    // casts
    int n4x = N_NODES * 128 / 4;
    k_cast_x<<<(n4x + TB - 1) / TB, TB, 0, stream>>>(x, xh, n4x);
    k_transpose_w<128><<<(128 * 256 + TB - 1) / TB, TB, 0, stream>>>(W1, w1t);
    k_transpose_w<256><<<(256 * 256 + TB - 1) / TB, TB, 0, stream>>>(W2, w2t);

    // layer 1
    k_mfma_gemm<128, 8><<<gridG, TB, 0, stream>>>(xh, w1t, as1, ad1, h1h, es1, ed1);
    k_agg1<<<N_NODES, TB, 0, stream>>>(h1h, es1, ed1, offsets, csr_src, b1, out1h);

    // layer 2
    k_mfma_gemm<256, 1><<<gridG, TB, 0, stream>>>(out1h, w2t, as2, ad2, h2h, es2, ed2);
    k_agg2<<<N_NODES, TB, 0, stream>>>(h2h, es2, ed2, offsets, csr_src, b2, out);
}

// Round 5
// 387.522 us; speedup vs baseline: 4.1292x; 1.1007x over previous
//
#include <hip/hip_runtime.h>
#include <math.h>

#define N_NODES 50000
#define E_ORIG  500000
#define E_TOT   550000
#define CAPE    128   // per-node LDS edge cache; degree > CAPE falls back to recompute
#define NB      196   // scan blocks: 196*256 = 50176 >= N_NODES

typedef _Float16 half8 __attribute__((ext_vector_type(8)));
typedef _Float16 half4 __attribute__((ext_vector_type(4)));
typedef float    v4f   __attribute__((ext_vector_type(4)));

// ------------------------------------------------------------------
// CSR build (group edges by destination node)
// ------------------------------------------------------------------
__global__ void k_zero(int* __restrict__ p, int n) {
    int i = blockIdx.x * blockDim.x + threadIdx.x;
    if (i < n) p[i] = 0;
}

__global__ void k_count(const int* __restrict__ ei, int* __restrict__ deg) {
    int e = blockIdx.x * blockDim.x + threadIdx.x;
    if (e >= E_TOT) return;
    int d = (e < E_ORIG) ? ei[E_ORIG + e] : (e - E_ORIG);
    atomicAdd(&deg[d], 1);
}

__global__ __launch_bounds__(256) void k_blocksum(const int* __restrict__ deg,
                                                  int* __restrict__ bsum) {
    int t = threadIdx.x;
    int i = blockIdx.x * 256 + t;
    int v = (i < N_NODES) ? deg[i] : 0;
#pragma unroll
    for (int mk = 1; mk < 64; mk <<= 1) v += __shfl_xor(v, mk, 64);
    __shared__ int ws[4];
    if ((t & 63) == 0) ws[t >> 6] = v;
    __syncthreads();
    if (t == 0) bsum[blockIdx.x] = ws[0] + ws[1] + ws[2] + ws[3];
}

__global__ __launch_bounds__(256) void k_scanbsum(const int* __restrict__ bsum,
                                                  int* __restrict__ boff) {
    __shared__ int s[256];
    int t = threadIdx.x;
    int v = (t < NB) ? bsum[t] : 0;
    s[t] = v;
    __syncthreads();
    for (int o = 1; o < 256; o <<= 1) {
        int x = (t >= o) ? s[t - o] : 0;
        __syncthreads();
        s[t] += x;
        __syncthreads();
    }
    if (t <= NB) boff[t] = (t == 0) ? 0 : s[t - 1];
}

__global__ __launch_bounds__(256) void k_offsets(const int* __restrict__ deg,
                                                 const int* __restrict__ boff,
                                                 int* __restrict__ offsets,
                                                 int* __restrict__ cur) {
    __shared__ int s[256];
    int t = threadIdx.x;
    int i = blockIdx.x * 256 + t;
    int v = (i < N_NODES) ? deg[i] : 0;
    s[t] = v;
    __syncthreads();
    for (int o = 1; o < 256; o <<= 1) {
        int x = (t >= o) ? s[t - o] : 0;
        __syncthreads();
        s[t] += x;
        __syncthreads();
    }
    int off = boff[blockIdx.x] + s[t] - v;  // exclusive
    if (i <= N_NODES) {
        offsets[i] = off;
        if (i < N_NODES) cur[i] = off;
    }
}

__global__ void k_scatter(const int* __restrict__ ei, int* __restrict__ cur,
                          int* __restrict__ csr_src) {
    int e = blockIdx.x * blockDim.x + threadIdx.x;
    if (e >= E_TOT) return;
    int s, d;
    if (e < E_ORIG) { s = ei[e]; d = ei[E_ORIG + e]; }
    else            { s = e - E_ORIG; d = s; }
    int slot = atomicAdd(&cur[d], 1);
    csr_src[slot] = s;
}

// ------------------------------------------------------------------
// Fused prep: X f32->f16 (float4->half4), W1/W2 transpose+cast
// ------------------------------------------------------------------
#define N4X (N_NODES * 128 / 4)
__global__ void k_prep(const float* __restrict__ X, _Float16* __restrict__ Xh,
                       const float* __restrict__ W1, _Float16* __restrict__ w1t,
                       const float* __restrict__ W2, _Float16* __restrict__ w2t) {
    int i = blockIdx.x * blockDim.x + threadIdx.x;
    if (i < N4X) {
        float4 v = ((const float4*)X)[i];
        ((half4*)Xh)[i] = (half4){(_Float16)v.x, (_Float16)v.y, (_Float16)v.z, (_Float16)v.w};
        return;
    }
    int j = i - N4X;
    if (j < 128 * 256) {
        int k = j >> 8, c = j & 255;
        w1t[(size_t)c * 128 + k] = (_Float16)W1[j];
        return;
    }
    j -= 128 * 256;
    if (j < 256 * 256) {
        int k = j >> 8, c = j & 255;
        w2t[(size_t)c * 256 + k] = (_Float16)W2[j];
    }
}

// ------------------------------------------------------------------
// MFMA GEMM + fused attention coefficients (unchanged from R4)
// ------------------------------------------------------------------
template <int K, int NH>
__global__ __launch_bounds__(256) void k_mfma_gemm(
    const _Float16* __restrict__ A, const _Float16* __restrict__ Bt,
    const float* __restrict__ a_s, const float* __restrict__ a_d,
    _Float16* __restrict__ H, float* __restrict__ es, float* __restrict__ ed) {
    int t = threadIdx.x, w = t >> 6, lane = t & 63;
    int quad = lane >> 4, l16 = lane & 15;
    int rh = w & 1, ch = w >> 1;
    int row0 = blockIdx.x * 64 + rh * 32;
    int colbase = ch * 128;

    v4f acc[2][8];
#pragma unroll
    for (int i = 0; i < 2; i++)
#pragma unroll
        for (int j = 0; j < 8; j++) acc[i][j] = (v4f){0.f, 0.f, 0.f, 0.f};

    int r0 = row0 + l16;      if (r0 >= N_NODES) r0 = N_NODES - 1;
    int r1 = row0 + 16 + l16; if (r1 >= N_NODES) r1 = N_NODES - 1;
    const half8* a0 = (const half8*)(A + (size_t)r0 * K + quad * 8);
    const half8* a1 = (const half8*)(A + (size_t)r1 * K + quad * 8);
    const half8* bp[8];
#pragma unroll
    for (int ct = 0; ct < 8; ct++)
        bp[ct] = (const half8*)(Bt + (size_t)(colbase + ct * 16 + l16) * K + quad * 8);

#pragma unroll
    for (int kc = 0; kc < K / 32; kc++) {
        half8 av0 = a0[kc * 4];
        half8 av1 = a1[kc * 4];
#pragma unroll
        for (int ct = 0; ct < 8; ct++) {
            half8 bv = bp[ct][kc * 4];
            acc[0][ct] = __builtin_amdgcn_mfma_f32_16x16x32_f16(av0, bv, acc[0][ct], 0, 0, 0);
            acc[1][ct] = __builtin_amdgcn_mfma_f32_16x16x32_f16(av1, bv, acc[1][ct], 0, 0, 0);
        }
    }

#pragma unroll
    for (int rt = 0; rt < 2; rt++) {
#pragma unroll
        for (int reg = 0; reg < 4; reg++) {
            int row = row0 + rt * 16 + quad * 4 + reg;
            if (row < N_NODES) {
#pragma unroll
                for (int ct = 0; ct < 8; ct++)
                    H[(size_t)row * 256 + colbase + ct * 16 + l16] = (_Float16)acc[rt][ct][reg];
            }
        }
    }

    float asv[8], adv[8];
#pragma unroll
    for (int ct = 0; ct < 8; ct++) {
        asv[ct] = a_s[colbase + ct * 16 + l16];
        adv[ct] = a_d[colbase + ct * 16 + l16];
    }

    if constexpr (NH == 8) {
#pragma unroll
        for (int rt = 0; rt < 2; rt++) {
#pragma unroll
            for (int hp = 0; hp < 4; hp++) {
#pragma unroll
                for (int reg = 0; reg < 4; reg++) {
                    float ps = acc[rt][2 * hp][reg] * asv[2 * hp] +
                               acc[rt][2 * hp + 1][reg] * asv[2 * hp + 1];
                    float pd = acc[rt][2 * hp][reg] * adv[2 * hp] +
                               acc[rt][2 * hp + 1][reg] * adv[2 * hp + 1];
#pragma unroll
                    for (int mk = 1; mk < 16; mk <<= 1) {
                        ps += __shfl_xor(ps, mk, 64);
                        pd += __shfl_xor(pd, mk, 64);
                    }
                    if (l16 == 0) {
                        int row = row0 + rt * 16 + quad * 4 + reg;
                        if (row < N_NODES) {
                            int head = ch * 4 + hp;
                            es[(size_t)row * 8 + head] = ps;
                            ed[(size_t)row * 8 + head] = pd;
                        }
                    }
                }
            }
        }
    } else {
        __shared__ float esp[2][64], edp[2][64];
#pragma unroll
        for (int rt = 0; rt < 2; rt++) {
#pragma unroll
            for (int reg = 0; reg < 4; reg++) {
                float ps = 0.f, pd = 0.f;
#pragma unroll
                for (int ct = 0; ct < 8; ct++) {
                    ps += acc[rt][ct][reg] * asv[ct];
                    pd += acc[rt][ct][reg] * adv[ct];
                }
#pragma unroll
                for (int mk = 1; mk < 16; mk <<= 1) {
                    ps += __shfl_xor(ps, mk, 64);
                    pd += __shfl_xor(pd, mk, 64);
                }
                if (l16 == 0) {
                    int lrow = rh * 32 + rt * 16 + quad * 4 + reg;
                    esp[ch][lrow] = ps;
                    edp[ch][lrow] = pd;
                }
            }
        }
        __syncthreads();
        if (t < 64) {
            int row = blockIdx.x * 64 + t;
            if (row < N_NODES) {
                es[row] = esp[0][t] + esp[1][t];
                ed[row] = edp[0][t] + edp[1][t];
            }
        }
    }
}

// ------------------------------------------------------------------
// Layer-1 aggregation. Phase A: unnormalized alphas (exp of leaky) in
// LDS + per-head reciprocal denominators. Phase B: wave-per-edge
// gather — lane loads half4 (8 B) so one wave covers the whole 512 B
// row in one dwordx2 instruction; 4 waves = 4 edges in flight, 2-edge
// unroll. Cross-wave combine via LDS partials.
// ------------------------------------------------------------------
__global__ __launch_bounds__(256) void k_agg1(
    const _Float16* __restrict__ H1, const float* __restrict__ es,
    const float* __restrict__ ed, const int* __restrict__ offsets,
    const int* __restrict__ csr_src, const float* __restrict__ b1,
    _Float16* __restrict__ out1) {
    int n = blockIdx.x, t = threadIdx.x;
    int w = t >> 6, lane = t & 63;
    int beg = offsets[n];
    int deg = offsets[n + 1] - beg;
    int ncap = deg < CAPE ? deg : CAPE;
    __shared__ int lsrc[CAPE];
    __shared__ float le[CAPE * 8];
    __shared__ float sed[8], rdn[8];
    __shared__ float wred[4][8];
    __shared__ float part[4][256];

    if (t < 8) sed[t] = ed[(size_t)n * 8 + t];
    for (int i = t; i < ncap; i += 256) lsrc[i] = csr_src[beg + i];
    __syncthreads();

    // phase A: alphas + denominators (32 edge-slots x 8 heads)
    int h8 = t & 7, slot = t >> 3;
    float sum = 0.f;
    for (int i = slot; i < ncap; i += 32) {
        int s = lsrc[i];
        float l = es[(size_t)s * 8 + h8] + sed[h8];
        l = l > 0.f ? l : 0.2f * l;
        float e = __expf(l);
        le[i * 8 + h8] = e;
        sum += e;
    }
    for (int i = CAPE + slot; i < deg; i += 32) {
        int s = csr_src[beg + i];
        float l = es[(size_t)s * 8 + h8] + sed[h8];
        l = l > 0.f ? l : 0.2f * l;
        sum += __expf(l);
    }
#pragma unroll
    for (int mk = 8; mk < 64; mk <<= 1) sum += __shfl_xor(sum, mk, 64);
    if ((t & 63) < 8) wred[t >> 6][h8] = sum;
    __syncthreads();
    if (t < 8)
        rdn[t] = 1.f / (wred[0][t] + wred[1][t] + wred[2][t] + wred[3][t] + 1e-16f);
    __syncthreads();

    // phase B: wave-per-edge gather; lane owns channels lane*4..lane*4+3
    int hB = lane >> 3;  // head of this lane's 4 channels
    float a0 = 0.f, a1 = 0.f, a2 = 0.f, a3 = 0.f;
    if (deg <= CAPE) {
        int i = w;
        for (; i + 4 < deg; i += 8) {
            int s0 = lsrc[i], s1 = lsrc[i + 4];
            float al0 = le[i * 8 + hB], al1 = le[(i + 4) * 8 + hB];
            half4 h0 = ((const half4*)(H1 + (size_t)s0 * 256))[lane];
            half4 h1 = ((const half4*)(H1 + (size_t)s1 * 256))[lane];
            a0 += al0 * (float)h0[0]; a1 += al0 * (float)h0[1];
            a2 += al0 * (float)h0[2]; a3 += al0 * (float)h0[3];
            a0 += al1 * (float)h1[0]; a1 += al1 * (float)h1[1];
            a2 += al1 * (float)h1[2]; a3 += al1 * (float)h1[3];
        }
        if (i < deg) {
            int s0 = lsrc[i];
            float al0 = le[i * 8 + hB];
            half4 h0 = ((const half4*)(H1 + (size_t)s0 * 256))[lane];
            a0 += al0 * (float)h0[0]; a1 += al0 * (float)h0[1];
            a2 += al0 * (float)h0[2]; a3 += al0 * (float)h0[3];
        }
    } else {
        for (int i = w; i < deg; i += 4) {
            int s0; float al0;
            if (i < CAPE) { s0 = lsrc[i]; al0 = le[i * 8 + hB]; }
            else {
                s0 = csr_src[beg + i];
                float l = es[(size_t)s0 * 8 + hB] + sed[hB];
                l = l > 0.f ? l : 0.2f * l;
                al0 = __expf(l);
            }
            half4 h0 = ((const half4*)(H1 + (size_t)s0 * 256))[lane];
            a0 += al0 * (float)h0[0]; a1 += al0 * (float)h0[1];
            a2 += al0 * (float)h0[2]; a3 += al0 * (float)h0[3];
        }
    }
    ((float4*)&part[w][0])[lane] = make_float4(a0, a1, a2, a3);
    __syncthreads();

    float tot = part[0][t] + part[1][t] + part[2][t] + part[3][t];
    float o = tot * rdn[t >> 5] + b1[t];
    o = o > 0.f ? o : __expf(o) - 1.f;  // ELU
    out1[(size_t)n * 256 + t] = (_Float16)o;
}

// ------------------------------------------------------------------
// Layer-2 aggregation: single head, same wave-per-edge structure.
// ------------------------------------------------------------------
__global__ __launch_bounds__(256) void k_agg2(
    const _Float16* __restrict__ H2, const float* __restrict__ es,
    const float* __restrict__ ed, const int* __restrict__ offsets,
    const int* __restrict__ csr_src, const float* __restrict__ b2,
    float* __restrict__ out) {
    int n = blockIdx.x, t = threadIdx.x;
    int w = t >> 6, lane = t & 63;
    int beg = offsets[n];
    int deg = offsets[n + 1] - beg;
    int ncap = deg < CAPE ? deg : CAPE;
    __shared__ int lsrc[CAPE];
    __shared__ float le[CAPE];
    __shared__ float wredf[4];
    __shared__ float srdn;
    __shared__ float part[4][256];
    float edn = ed[n];
    for (int i = t; i < ncap; i += 256) lsrc[i] = csr_src[beg + i];
    __syncthreads();

    float sum = 0.f;
    for (int i = t; i < ncap; i += 256) {
        int s = lsrc[i];
        float l = es[s] + edn; l = l > 0.f ? l : 0.2f * l;
        float e = __expf(l);
        le[i] = e;
        sum += e;
    }
    for (int i = CAPE + t; i < deg; i += 256) {
        int s = csr_src[beg + i];
        float l = es[s] + edn; l = l > 0.f ? l : 0.2f * l;
        sum += __expf(l);
    }
#pragma unroll
    for (int mk = 1; mk < 64; mk <<= 1) sum += __shfl_xor(sum, mk, 64);
    if ((t & 63) == 0) wredf[t >> 6] = sum;
    __syncthreads();
    if (t == 0) srdn = 1.f / (wredf[0] + wredf[1] + wredf[2] + wredf[3] + 1e-16f);
    __syncthreads();
    float rdn = srdn;

    float a0 = 0.f, a1 = 0.f, a2 = 0.f, a3 = 0.f;
    if (deg <= CAPE) {
        int i = w;
        for (; i + 4 < deg; i += 8) {
            int s0 = lsrc[i], s1 = lsrc[i + 4];
            float al0 = le[i], al1 = le[i + 4];
            half4 h0 = ((const half4*)(H2 + (size_t)s0 * 256))[lane];
            half4 h1 = ((const half4*)(H2 + (size_t)s1 * 256))[lane];
            a0 += al0 * (float)h0[0]; a1 += al0 * (float)h0[1];
            a2 += al0 * (float)h0[2]; a3 += al0 * (float)h0[3];
            a0 += al1 * (float)h1[0]; a1 += al1 * (float)h1[1];
            a2 += al1 * (float)h1[2]; a3 += al1 * (float)h1[3];
        }
        if (i < deg) {
            int s0 = lsrc[i];
            float al0 = le[i];
            half4 h0 = ((const half4*)(H2 + (size_t)s0 * 256))[lane];
            a0 += al0 * (float)h0[0]; a1 += al0 * (float)h0[1];
            a2 += al0 * (float)h0[2]; a3 += al0 * (float)h0[3];
        }
    } else {
        for (int i = w; i < deg; i += 4) {
            int s0; float al0;
            if (i < CAPE) { s0 = lsrc[i]; al0 = le[i]; }
            else {
                s0 = csr_src[beg + i];
                float l = es[s0] + edn;
                l = l > 0.f ? l : 0.2f * l;
                al0 = __expf(l);
            }
            half4 h0 = ((const half4*)(H2 + (size_t)s0 * 256))[lane];
            a0 += al0 * (float)h0[0]; a1 += al0 * (float)h0[1];
            a2 += al0 * (float)h0[2]; a3 += al0 * (float)h0[3];
        }
    }
    ((float4*)&part[w][0])[lane] = make_float4(a0, a1, a2, a3);
    __syncthreads();

    float tot = part[0][t] + part[1][t] + part[2][t] + part[3][t];
    out[(size_t)n * 256 + t] = tot * rdn + b2[t];
}

// ------------------------------------------------------------------
extern "C" void kernel_launch(void* const* d_in, const int* in_sizes, int n_in,
                              void* d_out, int out_size, void* d_ws, size_t ws_size,
                              hipStream_t stream) {
    const float* x   = (const float*)d_in[0];
    const int*   ei  = (const int*)d_in[1];
    const float* W1  = (const float*)d_in[2];
    const float* as1 = (const float*)d_in[3];
    const float* ad1 = (const float*)d_in[4];
    const float* b1  = (const float*)d_in[5];
    const float* W2  = (const float*)d_in[6];
    const float* as2 = (const float*)d_in[7];
    const float* ad2 = (const float*)d_in[8];
    const float* b2  = (const float*)d_in[9];
    float* out = (float*)d_out;

    char* ws = (char*)d_ws;
    size_t off = 0;
    auto alloc = [&](size_t bytes) {
        void* p = ws + off;
        off = (off + bytes + 255) & ~(size_t)255;
        return p;
    };
    _Float16* h1h     = (_Float16*)alloc((size_t)N_NODES * 256 * 2);
    _Float16* h2h     = (_Float16*)alloc((size_t)N_NODES * 256 * 2);
    _Float16* out1h   = (_Float16*)alloc((size_t)N_NODES * 256 * 2);
    _Float16* xh      = (_Float16*)alloc((size_t)N_NODES * 128 * 2);
    _Float16* w1t     = (_Float16*)alloc((size_t)128 * 256 * 2);
    _Float16* w2t     = (_Float16*)alloc((size_t)256 * 256 * 2);
    float*    es1     = (float*)alloc((size_t)N_NODES * 8 * 4);
    float*    ed1     = (float*)alloc((size_t)N_NODES * 8 * 4);
    float*    es2     = (float*)alloc((size_t)N_NODES * 4);
    float*    ed2     = (float*)alloc((size_t)N_NODES * 4);
    int*      deg     = (int*)alloc((size_t)N_NODES * 4);
    int*      offsets = (int*)alloc((size_t)(N_NODES + 1) * 4);
    int*      cur     = (int*)alloc((size_t)N_NODES * 4);
    int*      csr_src = (int*)alloc((size_t)E_TOT * 4);
    int*      bsum    = (int*)alloc((size_t)NB * 4);
    int*      boff    = (int*)alloc((size_t)(NB + 1) * 4);

    const int TB = 256;
    int gridN = (N_NODES + TB - 1) / TB;
    int gridE = (E_TOT + TB - 1) / TB;
    int gridG = (N_NODES + 63) / 64;

    // CSR build
    k_zero<<<gridN, TB, 0, stream>>>(deg, N_NODES);
    k_count<<<gridE, TB, 0, stream>>>(ei, deg);
    k_blocksum<<<NB, TB, 0, stream>>>(deg, bsum);
    k_scanbsum<<<1, TB, 0, stream>>>(bsum, boff);
    k_offsets<<<NB, TB, 0, stream>>>(deg, boff, offsets, cur);
    k_scatter<<<gridE, TB, 0, stream>>>(ei, cur, csr_src);

    // fused casts/transposes
    int prepN = N4X + 128 * 256 + 256 * 256;
    k_prep<<<(prepN + TB - 1) / TB, TB, 0, stream>>>(x, xh, W1, w1t, W2, w2t);

    // layer 1
    k_mfma_gemm<128, 8><<<gridG, TB, 0, stream>>>(xh, w1t, as1, ad1, h1h, es1, ed1);
    k_agg1<<<N_NODES, TB, 0, stream>>>(h1h, es1, ed1, offsets, csr_src, b1, out1h);

    // layer 2
    k_mfma_gemm<256, 1><<<gridG, TB, 0, stream>>>(out1h, w2t, as2, ad2, h2h, es2, ed2);
    k_agg2<<<N_NODES, TB, 0, stream>>>(h2h, es2, ed2, offsets, csr_src, b2, out);
}

// Round 6
// 340.571 us; speedup vs baseline: 4.6985x; 1.1379x over previous
//
#include <hip/hip_runtime.h>
#include <math.h>

#define N_NODES 50000
#define E_ORIG  500000
#define E_TOT   550000
#define NB      196   // scan blocks: 196*256 = 50176 >= N_NODES

typedef _Float16 half8 __attribute__((ext_vector_type(8)));
typedef _Float16 half4 __attribute__((ext_vector_type(4)));
typedef float    v4f   __attribute__((ext_vector_type(4)));

// ------------------------------------------------------------------
// CSR build (group edges by destination node)
// ------------------------------------------------------------------
__global__ void k_zero(int* __restrict__ p, int n) {
    int i = blockIdx.x * blockDim.x + threadIdx.x;
    if (i < n) p[i] = 0;
}

__global__ void k_count(const int* __restrict__ ei, int* __restrict__ deg) {
    int e = blockIdx.x * blockDim.x + threadIdx.x;
    if (e >= E_TOT) return;
    int d = (e < E_ORIG) ? ei[E_ORIG + e] : (e - E_ORIG);
    atomicAdd(&deg[d], 1);
}

__global__ __launch_bounds__(256) void k_blocksum(const int* __restrict__ deg,
                                                  int* __restrict__ bsum) {
    int t = threadIdx.x;
    int i = blockIdx.x * 256 + t;
    int v = (i < N_NODES) ? deg[i] : 0;
#pragma unroll
    for (int mk = 1; mk < 64; mk <<= 1) v += __shfl_xor(v, mk, 64);
    __shared__ int ws[4];
    if ((t & 63) == 0) ws[t >> 6] = v;
    __syncthreads();
    if (t == 0) bsum[blockIdx.x] = ws[0] + ws[1] + ws[2] + ws[3];
}

__global__ __launch_bounds__(256) void k_scanbsum(const int* __restrict__ bsum,
                                                  int* __restrict__ boff) {
    __shared__ int s[256];
    int t = threadIdx.x;
    int v = (t < NB) ? bsum[t] : 0;
    s[t] = v;
    __syncthreads();
    for (int o = 1; o < 256; o <<= 1) {
        int x = (t >= o) ? s[t - o] : 0;
        __syncthreads();
        s[t] += x;
        __syncthreads();
    }
    if (t <= NB) boff[t] = (t == 0) ? 0 : s[t - 1];
}

__global__ __launch_bounds__(256) void k_offsets(const int* __restrict__ deg,
                                                 const int* __restrict__ boff,
                                                 int* __restrict__ offsets,
                                                 int* __restrict__ cur) {
    __shared__ int s[256];
    int t = threadIdx.x;
    int i = blockIdx.x * 256 + t;
    int v = (i < N_NODES) ? deg[i] : 0;
    s[t] = v;
    __syncthreads();
    for (int o = 1; o < 256; o <<= 1) {
        int x = (t >= o) ? s[t - o] : 0;
        __syncthreads();
        s[t] += x;
        __syncthreads();
    }
    int off = boff[blockIdx.x] + s[t] - v;  // exclusive
    if (i <= N_NODES) {
        offsets[i] = off;
        if (i < N_NODES) cur[i] = off;
    }
}

__global__ void k_scatter(const int* __restrict__ ei, int* __restrict__ cur,
                          int* __restrict__ csr_src) {
    int e = blockIdx.x * blockDim.x + threadIdx.x;
    if (e >= E_TOT) return;
    int s, d;
    if (e < E_ORIG) { s = ei[e]; d = ei[E_ORIG + e]; }
    else            { s = e - E_ORIG; d = s; }
    int slot = atomicAdd(&cur[d], 1);
    csr_src[slot] = s;
}

// ------------------------------------------------------------------
// Fused prep: X f32->f16 (float4->half4), W1/W2 transpose+cast
// ------------------------------------------------------------------
#define N4X (N_NODES * 128 / 4)
__global__ void k_prep(const float* __restrict__ X, _Float16* __restrict__ Xh,
                       const float* __restrict__ W1, _Float16* __restrict__ w1t,
                       const float* __restrict__ W2, _Float16* __restrict__ w2t) {
    int i = blockIdx.x * blockDim.x + threadIdx.x;
    if (i < N4X) {
        float4 v = ((const float4*)X)[i];
        ((half4*)Xh)[i] = (half4){(_Float16)v.x, (_Float16)v.y, (_Float16)v.z, (_Float16)v.w};
        return;
    }
    int j = i - N4X;
    if (j < 128 * 256) {
        int k = j >> 8, c = j & 255;
        w1t[(size_t)c * 128 + k] = (_Float16)W1[j];
        return;
    }
    j -= 128 * 256;
    if (j < 256 * 256) {
        int k = j >> 8, c = j & 255;
        w2t[(size_t)c * 256 + k] = (_Float16)W2[j];
    }
}

// vs2[k] = sum_c W2[k,c]*a_src2[c]; vd2 likewise (for fused es2/ed2)
__global__ __launch_bounds__(256) void k_vw2(const float* __restrict__ W2,
                                             const float* __restrict__ as2,
                                             const float* __restrict__ ad2,
                                             float* __restrict__ vs2,
                                             float* __restrict__ vd2) {
    int k = threadIdx.x;
    float s = 0.f, d = 0.f;
    for (int c = 0; c < 256; c++) {
        float w = W2[(size_t)k * 256 + c];
        s += w * as2[c];
        d += w * ad2[c];
    }
    vs2[k] = s;
    vd2[k] = d;
}

// ------------------------------------------------------------------
// GEMM1: H[N,256] = Xh[N,128] @ w1t^T, f16 out + fused 8-head es/ed.
// Block 256 thr = 4 waves; tile 64 rows x 256 cols (validated R3-R5).
// ------------------------------------------------------------------
__global__ __launch_bounds__(256) void k_gemm1(
    const _Float16* __restrict__ A, const _Float16* __restrict__ Bt,
    const float* __restrict__ a_s, const float* __restrict__ a_d,
    _Float16* __restrict__ H, float* __restrict__ es, float* __restrict__ ed) {
    constexpr int K = 128;
    int t = threadIdx.x, w = t >> 6, lane = t & 63;
    int quad = lane >> 4, l16 = lane & 15;
    int rh = w & 1, ch = w >> 1;
    int row0 = blockIdx.x * 64 + rh * 32;
    int colbase = ch * 128;

    v4f acc[2][8];
#pragma unroll
    for (int i = 0; i < 2; i++)
#pragma unroll
        for (int j = 0; j < 8; j++) acc[i][j] = (v4f){0.f, 0.f, 0.f, 0.f};

    int r0 = row0 + l16;      if (r0 >= N_NODES) r0 = N_NODES - 1;
    int r1 = row0 + 16 + l16; if (r1 >= N_NODES) r1 = N_NODES - 1;
    const half8* a0 = (const half8*)(A + (size_t)r0 * K + quad * 8);
    const half8* a1 = (const half8*)(A + (size_t)r1 * K + quad * 8);
    const half8* bp[8];
#pragma unroll
    for (int ct = 0; ct < 8; ct++)
        bp[ct] = (const half8*)(Bt + (size_t)(colbase + ct * 16 + l16) * K + quad * 8);

#pragma unroll
    for (int kc = 0; kc < K / 32; kc++) {
        half8 av0 = a0[kc * 4];
        half8 av1 = a1[kc * 4];
#pragma unroll
        for (int ct = 0; ct < 8; ct++) {
            half8 bv = bp[ct][kc * 4];
            acc[0][ct] = __builtin_amdgcn_mfma_f32_16x16x32_f16(av0, bv, acc[0][ct], 0, 0, 0);
            acc[1][ct] = __builtin_amdgcn_mfma_f32_16x16x32_f16(av1, bv, acc[1][ct], 0, 0, 0);
        }
    }

#pragma unroll
    for (int rt = 0; rt < 2; rt++) {
#pragma unroll
        for (int reg = 0; reg < 4; reg++) {
            int row = row0 + rt * 16 + quad * 4 + reg;
            if (row < N_NODES) {
#pragma unroll
                for (int ct = 0; ct < 8; ct++)
                    H[(size_t)row * 256 + colbase + ct * 16 + l16] = (_Float16)acc[rt][ct][reg];
            }
        }
    }

    float asv[8], adv[8];
#pragma unroll
    for (int ct = 0; ct < 8; ct++) {
        asv[ct] = a_s[colbase + ct * 16 + l16];
        adv[ct] = a_d[colbase + ct * 16 + l16];
    }

#pragma unroll
    for (int rt = 0; rt < 2; rt++) {
#pragma unroll
        for (int hp = 0; hp < 4; hp++) {
#pragma unroll
            for (int reg = 0; reg < 4; reg++) {
                float ps = acc[rt][2 * hp][reg] * asv[2 * hp] +
                           acc[rt][2 * hp + 1][reg] * asv[2 * hp + 1];
                float pd = acc[rt][2 * hp][reg] * adv[2 * hp] +
                           acc[rt][2 * hp + 1][reg] * adv[2 * hp + 1];
#pragma unroll
                for (int mk = 1; mk < 16; mk <<= 1) {
                    ps += __shfl_xor(ps, mk, 64);
                    pd += __shfl_xor(pd, mk, 64);
                }
                if (l16 == 0) {
                    int row = row0 + rt * 16 + quad * 4 + reg;
                    if (row < N_NODES) {
                        int head = ch * 4 + hp;
                        es[(size_t)row * 8 + head] = ps;
                        ed[(size_t)row * 8 + head] = pd;
                    }
                }
            }
        }
    }
}

// ------------------------------------------------------------------
// GEMM2: OUT[N,256] = A[N,256] @ Bt^T + bias, f32 out (final output).
// ------------------------------------------------------------------
__global__ __launch_bounds__(256) void k_gemm2(
    const _Float16* __restrict__ A, const _Float16* __restrict__ Bt,
    const float* __restrict__ bias, float* __restrict__ OUT) {
    constexpr int K = 256;
    int t = threadIdx.x, w = t >> 6, lane = t & 63;
    int quad = lane >> 4, l16 = lane & 15;
    int rh = w & 1, ch = w >> 1;
    int row0 = blockIdx.x * 64 + rh * 32;
    int colbase = ch * 128;

    v4f acc[2][8];
#pragma unroll
    for (int i = 0; i < 2; i++)
#pragma unroll
        for (int j = 0; j < 8; j++) acc[i][j] = (v4f){0.f, 0.f, 0.f, 0.f};

    int r0 = row0 + l16;      if (r0 >= N_NODES) r0 = N_NODES - 1;
    int r1 = row0 + 16 + l16; if (r1 >= N_NODES) r1 = N_NODES - 1;
    const half8* a0 = (const half8*)(A + (size_t)r0 * K + quad * 8);
    const half8* a1 = (const half8*)(A + (size_t)r1 * K + quad * 8);
    const half8* bp[8];
#pragma unroll
    for (int ct = 0; ct < 8; ct++)
        bp[ct] = (const half8*)(Bt + (size_t)(colbase + ct * 16 + l16) * K + quad * 8);

#pragma unroll
    for (int kc = 0; kc < K / 32; kc++) {
        half8 av0 = a0[kc * 4];
        half8 av1 = a1[kc * 4];
#pragma unroll
        for (int ct = 0; ct < 8; ct++) {
            half8 bv = bp[ct][kc * 4];
            acc[0][ct] = __builtin_amdgcn_mfma_f32_16x16x32_f16(av0, bv, acc[0][ct], 0, 0, 0);
            acc[1][ct] = __builtin_amdgcn_mfma_f32_16x16x32_f16(av1, bv, acc[1][ct], 0, 0, 0);
        }
    }

    float bv[8];
#pragma unroll
    for (int ct = 0; ct < 8; ct++) bv[ct] = bias[colbase + ct * 16 + l16];

#pragma unroll
    for (int rt = 0; rt < 2; rt++) {
#pragma unroll
        for (int reg = 0; reg < 4; reg++) {
            int row = row0 + rt * 16 + quad * 4 + reg;
            if (row < N_NODES) {
#pragma unroll
                for (int ct = 0; ct < 8; ct++)
                    OUT[(size_t)row * 256 + colbase + ct * 16 + l16] =
                        acc[rt][ct][reg] + bv[ct];
            }
        }
    }
}

// ------------------------------------------------------------------
// Layer-1 aggregation: single-pass, wave-per-node, no barriers.
// out[n] = (sum_e w_e * H1[s_e]) / (sum_e w_e),  w_e = exp(leaky(es+ed))
// Every lane computes w_e itself -> denominator needs no reduction.
// Lane owns 4 channels (half4). Epilogue: +b1, ELU, f16 store, plus
// fused es2/ed2 = out1 . vs2/vd2 (wave shfl reduce).
// ------------------------------------------------------------------
__global__ __launch_bounds__(256) void k_agg1(
    const _Float16* __restrict__ H1, const float* __restrict__ es,
    const float* __restrict__ ed, const int* __restrict__ offsets,
    const int* __restrict__ csr_src, const float* __restrict__ b1,
    const float* __restrict__ vs2, const float* __restrict__ vd2,
    _Float16* __restrict__ out1, float* __restrict__ es2,
    float* __restrict__ ed2) {
    int t = threadIdx.x, w = t >> 6, lane = t & 63;
    int n = blockIdx.x * 4 + w;  // grid 12500 x 4 waves = 50000 exactly
    int hB = lane >> 3;          // head of this lane's 4 channels
    int beg = offsets[n];
    int deg = offsets[n + 1] - beg;
    float edl = ed[(size_t)n * 8 + hB];

    const half4* __restrict__ Hl = (const half4*)H1 + lane;
    float a0 = 0.f, a1 = 0.f, a2 = 0.f, a3 = 0.f, den = 0.f;

    for (int base = 0; base < deg; base += 64) {
        int rem = deg - base; if (rem > 64) rem = 64;
        int idx = beg + base + lane;
        if (idx >= E_TOT) idx = E_TOT - 1;
        int sreg = csr_src[idx];
        int i = 0;
        for (; i + 1 < rem; i += 2) {
            int s0 = __shfl(sreg, i);
            int s1 = __shfl(sreg, i + 1);
            float l0 = es[(size_t)s0 * 8 + hB] + edl;
            float l1 = es[(size_t)s1 * 8 + hB] + edl;
            l0 = l0 > 0.f ? l0 : 0.2f * l0;
            l1 = l1 > 0.f ? l1 : 0.2f * l1;
            float w0 = __expf(l0), w1 = __expf(l1);
            half4 h0 = Hl[(size_t)s0 * 64];
            half4 h1 = Hl[(size_t)s1 * 64];
            a0 += w0 * (float)h0[0]; a1 += w0 * (float)h0[1];
            a2 += w0 * (float)h0[2]; a3 += w0 * (float)h0[3];
            a0 += w1 * (float)h1[0]; a1 += w1 * (float)h1[1];
            a2 += w1 * (float)h1[2]; a3 += w1 * (float)h1[3];
            den += w0 + w1;
        }
        if (i < rem) {
            int s0 = __shfl(sreg, i);
            float l0 = es[(size_t)s0 * 8 + hB] + edl;
            l0 = l0 > 0.f ? l0 : 0.2f * l0;
            float w0 = __expf(l0);
            half4 h0 = Hl[(size_t)s0 * 64];
            a0 += w0 * (float)h0[0]; a1 += w0 * (float)h0[1];
            a2 += w0 * (float)h0[2]; a3 += w0 * (float)h0[3];
            den += w0;
        }
    }

    float r = 1.f / (den + 1e-16f);
    float4 bb = ((const float4*)b1)[lane];
    float o0 = a0 * r + bb.x, o1 = a1 * r + bb.y;
    float o2 = a2 * r + bb.z, o3 = a3 * r + bb.w;
    o0 = o0 > 0.f ? o0 : __expf(o0) - 1.f;
    o1 = o1 > 0.f ? o1 : __expf(o1) - 1.f;
    o2 = o2 > 0.f ? o2 : __expf(o2) - 1.f;
    o3 = o3 > 0.f ? o3 : __expf(o3) - 1.f;
    ((half4*)(out1 + (size_t)n * 256))[lane] =
        (half4){(_Float16)o0, (_Float16)o1, (_Float16)o2, (_Float16)o3};

    // fused layer-2 attention coefficients
    float4 vs = ((const float4*)vs2)[lane];
    float4 vd = ((const float4*)vd2)[lane];
    float ps = o0 * vs.x + o1 * vs.y + o2 * vs.z + o3 * vs.w;
    float pd = o0 * vd.x + o1 * vd.y + o2 * vd.z + o3 * vd.w;
#pragma unroll
    for (int mk = 1; mk < 64; mk <<= 1) {
        ps += __shfl_xor(ps, mk, 64);
        pd += __shfl_xor(pd, mk, 64);
    }
    if (lane == 0) { es2[n] = ps; ed2[n] = pd; }
}

// ------------------------------------------------------------------
// Layer-2 aggregation: single-pass wave-per-node on out1 rows
// (linearity: (sum a*out1[s]) @ W2 == sum a*(out1@W2)[s]).
// Writes normalized aggregate as f16 -> GEMM2 input.
// ------------------------------------------------------------------
__global__ __launch_bounds__(256) void k_agg2(
    const _Float16* __restrict__ O1, const float* __restrict__ es2,
    const float* __restrict__ ed2, const int* __restrict__ offsets,
    const int* __restrict__ csr_src, _Float16* __restrict__ xagg) {
    int t = threadIdx.x, w = t >> 6, lane = t & 63;
    int n = blockIdx.x * 4 + w;
    int beg = offsets[n];
    int deg = offsets[n + 1] - beg;
    float edn = ed2[n];

    const half4* __restrict__ Ol = (const half4*)O1 + lane;
    float a0 = 0.f, a1 = 0.f, a2 = 0.f, a3 = 0.f, den = 0.f;

    for (int base = 0; base < deg; base += 64) {
        int rem = deg - base; if (rem > 64) rem = 64;
        int idx = beg + base + lane;
        if (idx >= E_TOT) idx = E_TOT - 1;
        int sreg = csr_src[idx];
        int i = 0;
        for (; i + 1 < rem; i += 2) {
            int s0 = __shfl(sreg, i);
            int s1 = __shfl(sreg, i + 1);
            float l0 = es2[s0] + edn;
            float l1 = es2[s1] + edn;
            l0 = l0 > 0.f ? l0 : 0.2f * l0;
            l1 = l1 > 0.f ? l1 : 0.2f * l1;
            float w0 = __expf(l0), w1 = __expf(l1);
            half4 h0 = Ol[(size_t)s0 * 64];
            half4 h1 = Ol[(size_t)s1 * 64];
            a0 += w0 * (float)h0[0]; a1 += w0 * (float)h0[1];
            a2 += w0 * (float)h0[2]; a3 += w0 * (float)h0[3];
            a0 += w1 * (float)h1[0]; a1 += w1 * (float)h1[1];
            a2 += w1 * (float)h1[2]; a3 += w1 * (float)h1[3];
            den += w0 + w1;
        }
        if (i < rem) {
            int s0 = __shfl(sreg, i);
            float l0 = es2[s0] + edn;
            l0 = l0 > 0.f ? l0 : 0.2f * l0;
            float w0 = __expf(l0);
            half4 h0 = Ol[(size_t)s0 * 64];
            a0 += w0 * (float)h0[0]; a1 += w0 * (float)h0[1];
            a2 += w0 * (float)h0[2]; a3 += w0 * (float)h0[3];
            den += w0;
        }
    }

    float r = 1.f / (den + 1e-16f);
    ((half4*)(xagg + (size_t)n * 256))[lane] =
        (half4){(_Float16)(a0 * r), (_Float16)(a1 * r),
                (_Float16)(a2 * r), (_Float16)(a3 * r)};
}

// ------------------------------------------------------------------
extern "C" void kernel_launch(void* const* d_in, const int* in_sizes, int n_in,
                              void* d_out, int out_size, void* d_ws, size_t ws_size,
                              hipStream_t stream) {
    const float* x   = (const float*)d_in[0];
    const int*   ei  = (const int*)d_in[1];
    const float* W1  = (const float*)d_in[2];
    const float* as1 = (const float*)d_in[3];
    const float* ad1 = (const float*)d_in[4];
    const float* b1  = (const float*)d_in[5];
    const float* W2  = (const float*)d_in[6];
    const float* as2 = (const float*)d_in[7];
    const float* ad2 = (const float*)d_in[8];
    const float* b2  = (const float*)d_in[9];
    float* out = (float*)d_out;

    char* ws = (char*)d_ws;
    size_t off = 0;
    auto alloc = [&](size_t bytes) {
        void* p = ws + off;
        off = (off + bytes + 255) & ~(size_t)255;
        return p;
    };
    _Float16* h1h     = (_Float16*)alloc((size_t)N_NODES * 256 * 2);
    _Float16* out1h   = (_Float16*)alloc((size_t)N_NODES * 256 * 2);
    _Float16* xagg    = (_Float16*)alloc((size_t)N_NODES * 256 * 2);
    _Float16* xh      = (_Float16*)alloc((size_t)N_NODES * 128 * 2);
    _Float16* w1t     = (_Float16*)alloc((size_t)128 * 256 * 2);
    _Float16* w2t     = (_Float16*)alloc((size_t)256 * 256 * 2);
    float*    es1     = (float*)alloc((size_t)N_NODES * 8 * 4);
    float*    ed1     = (float*)alloc((size_t)N_NODES * 8 * 4);
    float*    es2     = (float*)alloc((size_t)N_NODES * 4);
    float*    ed2     = (float*)alloc((size_t)N_NODES * 4);
    float*    vs2     = (float*)alloc(256 * 4);
    float*    vd2     = (float*)alloc(256 * 4);
    int*      deg     = (int*)alloc((size_t)N_NODES * 4);
    int*      offsets = (int*)alloc((size_t)(N_NODES + 1) * 4);
    int*      cur     = (int*)alloc((size_t)N_NODES * 4);
    int*      csr_src = (int*)alloc((size_t)E_TOT * 4);
    int*      bsum    = (int*)alloc((size_t)NB * 4);
    int*      boff    = (int*)alloc((size_t)(NB + 1) * 4);

    const int TB = 256;
    int gridN = (N_NODES + TB - 1) / TB;
    int gridE = (E_TOT + TB - 1) / TB;
    int gridG = (N_NODES + 63) / 64;
    int gridA = N_NODES / 4;  // wave-per-node

    // CSR build
    k_zero<<<gridN, TB, 0, stream>>>(deg, N_NODES);
    k_count<<<gridE, TB, 0, stream>>>(ei, deg);
    k_blocksum<<<NB, TB, 0, stream>>>(deg, bsum);
    k_scanbsum<<<1, TB, 0, stream>>>(bsum, boff);
    k_offsets<<<NB, TB, 0, stream>>>(deg, boff, offsets, cur);
    k_scatter<<<gridE, TB, 0, stream>>>(ei, cur, csr_src);

    // prep: casts/transposes + layer-2 attention vectors
    int prepN = N4X + 128 * 256 + 256 * 256;
    k_prep<<<(prepN + TB - 1) / TB, TB, 0, stream>>>(x, xh, W1, w1t, W2, w2t);
    k_vw2<<<1, TB, 0, stream>>>(W2, as2, ad2, vs2, vd2);

    // layer 1
    k_gemm1<<<gridG, TB, 0, stream>>>(xh, w1t, as1, ad1, h1h, es1, ed1);
    k_agg1<<<gridA, TB, 0, stream>>>(h1h, es1, ed1, offsets, csr_src, b1,
                                     vs2, vd2, out1h, es2, ed2);

    // layer 2: aggregate first (linearity), then GEMM straight to d_out
    k_agg2<<<gridA, TB, 0, stream>>>(out1h, es2, ed2, offsets, csr_src, xagg);
    k_gemm2<<<gridG, TB, 0, stream>>>(xagg, w2t, b2, out);
}

// Round 7
// 329.026 us; speedup vs baseline: 4.8633x; 1.0351x over previous
//
#include <hip/hip_runtime.h>
#include <math.h>

#define N_NODES 50000
#define E_ORIG  500000
#define E_TOT   550000
#define NB      196   // scan blocks: 196*256 = 50176 >= N_NODES

typedef _Float16 half8 __attribute__((ext_vector_type(8)));
typedef _Float16 half4 __attribute__((ext_vector_type(4)));
typedef float    v4f   __attribute__((ext_vector_type(4)));

// ------------------------------------------------------------------
// CSR build (group edges by destination node)
// ------------------------------------------------------------------
__global__ void k_zero(int* __restrict__ p, int n) {
    int i = blockIdx.x * blockDim.x + threadIdx.x;
    if (i < n) p[i] = 0;
}

__global__ void k_count(const int* __restrict__ ei, int* __restrict__ deg) {
    int e = blockIdx.x * blockDim.x + threadIdx.x;
    if (e >= E_TOT) return;
    int d = (e < E_ORIG) ? ei[E_ORIG + e] : (e - E_ORIG);
    atomicAdd(&deg[d], 1);
}

__global__ __launch_bounds__(256) void k_blocksum(const int* __restrict__ deg,
                                                  int* __restrict__ bsum) {
    int t = threadIdx.x;
    int i = blockIdx.x * 256 + t;
    int v = (i < N_NODES) ? deg[i] : 0;
#pragma unroll
    for (int mk = 1; mk < 64; mk <<= 1) v += __shfl_xor(v, mk, 64);
    __shared__ int ws[4];
    if ((t & 63) == 0) ws[t >> 6] = v;
    __syncthreads();
    if (t == 0) bsum[blockIdx.x] = ws[0] + ws[1] + ws[2] + ws[3];
}

__global__ __launch_bounds__(256) void k_scanbsum(const int* __restrict__ bsum,
                                                  int* __restrict__ boff) {
    __shared__ int s[256];
    int t = threadIdx.x;
    int v = (t < NB) ? bsum[t] : 0;
    s[t] = v;
    __syncthreads();
    for (int o = 1; o < 256; o <<= 1) {
        int x = (t >= o) ? s[t - o] : 0;
        __syncthreads();
        s[t] += x;
        __syncthreads();
    }
    if (t <= NB) boff[t] = (t == 0) ? 0 : s[t - 1];
}

__global__ __launch_bounds__(256) void k_offsets(const int* __restrict__ deg,
                                                 const int* __restrict__ boff,
                                                 int* __restrict__ offsets,
                                                 int* __restrict__ cur) {
    __shared__ int s[256];
    int t = threadIdx.x;
    int i = blockIdx.x * 256 + t;
    int v = (i < N_NODES) ? deg[i] : 0;
    s[t] = v;
    __syncthreads();
    for (int o = 1; o < 256; o <<= 1) {
        int x = (t >= o) ? s[t - o] : 0;
        __syncthreads();
        s[t] += x;
        __syncthreads();
    }
    int off = boff[blockIdx.x] + s[t] - v;  // exclusive
    if (i <= N_NODES) {
        offsets[i] = off;
        if (i < N_NODES) cur[i] = off;
    }
}

__global__ void k_scatter(const int* __restrict__ ei, int* __restrict__ cur,
                          int* __restrict__ csr_src) {
    int e = blockIdx.x * blockDim.x + threadIdx.x;
    if (e >= E_TOT) return;
    int s, d;
    if (e < E_ORIG) { s = ei[e]; d = ei[E_ORIG + e]; }
    else            { s = e - E_ORIG; d = s; }
    int slot = atomicAdd(&cur[d], 1);
    csr_src[slot] = s;
}

// ------------------------------------------------------------------
// Fused prep: W1/W2 transpose+cast, vs2/vd2 = W2 @ a_{src,dst}2
// ------------------------------------------------------------------
__global__ void k_prepw(const float* __restrict__ W1, const float* __restrict__ W2,
                        const float* __restrict__ as2, const float* __restrict__ ad2,
                        _Float16* __restrict__ w1t, _Float16* __restrict__ w2t,
                        float* __restrict__ vs2, float* __restrict__ vd2) {
    int i = blockIdx.x * blockDim.x + threadIdx.x;
    if (i < 128 * 256) {
        int k = i >> 8, c = i & 255;
        w1t[(size_t)c * 128 + k] = (_Float16)W1[i];
        return;
    }
    int j = i - 128 * 256;
    if (j < 256 * 256) {
        int k = j >> 8, c = j & 255;
        w2t[(size_t)c * 256 + k] = (_Float16)W2[j];
        return;
    }
    int k = j - 256 * 256;
    if (k < 256) {
        float s = 0.f, d = 0.f;
        for (int c = 0; c < 256; c++) {
            float w = W2[(size_t)k * 256 + c];
            s += w * as2[c];
            d += w * ad2[c];
        }
        vs2[k] = s;
        vd2[k] = d;
    }
}

// ------------------------------------------------------------------
// GEMM1: H[N,256] = cvt16(X[N,128]) @ w1t^T, f16 out via LDS-staged
// streaming stores + fused 8-head es/ed.
// Block = 4 waves, tile 32 rows x 256 cols; wave w: cols w*64..+64.
// acc[rt][ct]: rows rt*16+quad*4+reg, col ct*16+l16 (C layout).
// ------------------------------------------------------------------
__global__ __launch_bounds__(256) void k_gemm1(
    const float* __restrict__ X, const _Float16* __restrict__ Bt,
    const float* __restrict__ a_s, const float* __restrict__ a_d,
    _Float16* __restrict__ H, float* __restrict__ es, float* __restrict__ ed) {
    int t = threadIdx.x, w = t >> 6, lane = t & 63;
    int quad = lane >> 4, l16 = lane & 15;
    int row0 = blockIdx.x * 32;
    int colbase = w * 64;

    v4f acc[2][4];
#pragma unroll
    for (int i = 0; i < 2; i++)
#pragma unroll
        for (int j = 0; j < 4; j++) acc[i][j] = (v4f){0.f, 0.f, 0.f, 0.f};

    int r0 = row0 + l16;      if (r0 >= N_NODES) r0 = N_NODES - 1;
    int r1 = row0 + 16 + l16; if (r1 >= N_NODES) r1 = N_NODES - 1;
    const float4* a0p = (const float4*)(X + (size_t)r0 * 128) + quad * 2;
    const float4* a1p = (const float4*)(X + (size_t)r1 * 128) + quad * 2;
    const half8* bp[4];
#pragma unroll
    for (int ct = 0; ct < 4; ct++)
        bp[ct] = (const half8*)(Bt + (size_t)(colbase + ct * 16 + l16) * 128 + quad * 8);

#pragma unroll
    for (int kc = 0; kc < 4; kc++) {
        float4 f0 = a0p[kc * 8], f1 = a0p[kc * 8 + 1];
        float4 f2 = a1p[kc * 8], f3 = a1p[kc * 8 + 1];
        half8 av0 = (half8){(_Float16)f0.x, (_Float16)f0.y, (_Float16)f0.z, (_Float16)f0.w,
                            (_Float16)f1.x, (_Float16)f1.y, (_Float16)f1.z, (_Float16)f1.w};
        half8 av1 = (half8){(_Float16)f2.x, (_Float16)f2.y, (_Float16)f2.z, (_Float16)f2.w,
                            (_Float16)f3.x, (_Float16)f3.y, (_Float16)f3.z, (_Float16)f3.w};
#pragma unroll
        for (int ct = 0; ct < 4; ct++) {
            half8 bv = bp[ct][kc * 4];
            acc[0][ct] = __builtin_amdgcn_mfma_f32_16x16x32_f16(av0, bv, acc[0][ct], 0, 0, 0);
            acc[1][ct] = __builtin_amdgcn_mfma_f32_16x16x32_f16(av1, bv, acc[1][ct], 0, 0, 0);
        }
    }

    // fused attention coefficients: wave w owns heads 2w (ct 0,1) and 2w+1 (ct 2,3)
    float asv[4], adv[4];
#pragma unroll
    for (int ct = 0; ct < 4; ct++) {
        asv[ct] = a_s[colbase + ct * 16 + l16];
        adv[ct] = a_d[colbase + ct * 16 + l16];
    }
#pragma unroll
    for (int rt = 0; rt < 2; rt++) {
#pragma unroll
        for (int hp = 0; hp < 2; hp++) {
#pragma unroll
            for (int reg = 0; reg < 4; reg++) {
                float ps = acc[rt][2 * hp][reg] * asv[2 * hp] +
                           acc[rt][2 * hp + 1][reg] * asv[2 * hp + 1];
                float pd = acc[rt][2 * hp][reg] * adv[2 * hp] +
                           acc[rt][2 * hp + 1][reg] * adv[2 * hp + 1];
#pragma unroll
                for (int mk = 1; mk < 16; mk <<= 1) {
                    ps += __shfl_xor(ps, mk, 64);
                    pd += __shfl_xor(pd, mk, 64);
                }
                if (l16 == 0) {
                    int row = row0 + rt * 16 + quad * 4 + reg;
                    if (row < N_NODES) {
                        int head = w * 2 + hp;
                        es[(size_t)row * 8 + head] = ps;
                        ed[(size_t)row * 8 + head] = pd;
                    }
                }
            }
        }
    }

    // LDS-staged f16 store: scattered C layout -> linear 1 KB/wave writes
    __shared__ _Float16 SH[32][264];
#pragma unroll
    for (int rt = 0; rt < 2; rt++)
#pragma unroll
        for (int ct = 0; ct < 4; ct++)
#pragma unroll
            for (int reg = 0; reg < 4; reg++)
                SH[rt * 16 + quad * 4 + reg][colbase + ct * 16 + l16] =
                    (_Float16)acc[rt][ct][reg];
    __syncthreads();
#pragma unroll
    for (int j = 0; j < 4; j++) {
        int c = j * 256 + t;
        int row = c >> 5, col8 = c & 31;
        int gr = row0 + row;
        if (gr < N_NODES)
            *(half8*)(H + (size_t)gr * 256 + col8 * 8) = *(const half8*)&SH[row][col8 * 8];
    }
}

// ------------------------------------------------------------------
// GEMM2: OUT[N,256] = A[N,256] @ w2t^T + bias, f32 out via LDS-staged
// streaming stores (final output).
// ------------------------------------------------------------------
__global__ __launch_bounds__(256) void k_gemm2(
    const _Float16* __restrict__ A, const _Float16* __restrict__ Bt,
    const float* __restrict__ bias, float* __restrict__ OUT) {
    int t = threadIdx.x, w = t >> 6, lane = t & 63;
    int quad = lane >> 4, l16 = lane & 15;
    int row0 = blockIdx.x * 32;
    int colbase = w * 64;

    v4f acc[2][4];
#pragma unroll
    for (int i = 0; i < 2; i++)
#pragma unroll
        for (int j = 0; j < 4; j++) acc[i][j] = (v4f){0.f, 0.f, 0.f, 0.f};

    int r0 = row0 + l16;      if (r0 >= N_NODES) r0 = N_NODES - 1;
    int r1 = row0 + 16 + l16; if (r1 >= N_NODES) r1 = N_NODES - 1;
    const half8* a0 = (const half8*)(A + (size_t)r0 * 256 + quad * 8);
    const half8* a1 = (const half8*)(A + (size_t)r1 * 256 + quad * 8);
    const half8* bp[4];
#pragma unroll
    for (int ct = 0; ct < 4; ct++)
        bp[ct] = (const half8*)(Bt + (size_t)(colbase + ct * 16 + l16) * 256 + quad * 8);

#pragma unroll
    for (int kc = 0; kc < 8; kc++) {
        half8 av0 = a0[kc * 4];
        half8 av1 = a1[kc * 4];
#pragma unroll
        for (int ct = 0; ct < 4; ct++) {
            half8 bv = bp[ct][kc * 4];
            acc[0][ct] = __builtin_amdgcn_mfma_f32_16x16x32_f16(av0, bv, acc[0][ct], 0, 0, 0);
            acc[1][ct] = __builtin_amdgcn_mfma_f32_16x16x32_f16(av1, bv, acc[1][ct], 0, 0, 0);
        }
    }

    __shared__ float SF[32][260];
#pragma unroll
    for (int rt = 0; rt < 2; rt++)
#pragma unroll
        for (int ct = 0; ct < 4; ct++)
#pragma unroll
            for (int reg = 0; reg < 4; reg++)
                SF[rt * 16 + quad * 4 + reg][colbase + ct * 16 + l16] = acc[rt][ct][reg];
    __syncthreads();
#pragma unroll
    for (int j = 0; j < 8; j++) {
        int c = j * 256 + t;
        int row = c >> 6, c4 = c & 63;
        int gr = row0 + row;
        if (gr < N_NODES) {
            float4 v = *(const float4*)&SF[row][c4 * 4];
            float4 bb = ((const float4*)bias)[c4];
            float4 o = make_float4(v.x + bb.x, v.y + bb.y, v.z + bb.z, v.w + bb.w);
            *(float4*)(OUT + (size_t)gr * 256 + c4 * 4) = o;
        }
    }
}

// ------------------------------------------------------------------
// Layer-1 aggregation: single-pass, wave-per-node, no barriers
// (validated R6). Fused es2/ed2 epilogue.
// ------------------------------------------------------------------
__global__ __launch_bounds__(256) void k_agg1(
    const _Float16* __restrict__ H1, const float* __restrict__ es,
    const float* __restrict__ ed, const int* __restrict__ offsets,
    const int* __restrict__ csr_src, const float* __restrict__ b1,
    const float* __restrict__ vs2, const float* __restrict__ vd2,
    _Float16* __restrict__ out1, float* __restrict__ es2,
    float* __restrict__ ed2) {
    int t = threadIdx.x, w = t >> 6, lane = t & 63;
    int n = blockIdx.x * 4 + w;  // grid 12500 x 4 waves = 50000 exactly
    int hB = lane >> 3;          // head of this lane's 4 channels
    int beg = offsets[n];
    int deg = offsets[n + 1] - beg;
    float edl = ed[(size_t)n * 8 + hB];

    const half4* __restrict__ Hl = (const half4*)H1 + lane;
    float a0 = 0.f, a1 = 0.f, a2 = 0.f, a3 = 0.f, den = 0.f;

    for (int base = 0; base < deg; base += 64) {
        int rem = deg - base; if (rem > 64) rem = 64;
        int idx = beg + base + lane;
        if (idx >= E_TOT) idx = E_TOT - 1;
        int sreg = csr_src[idx];
        int i = 0;
        for (; i + 1 < rem; i += 2) {
            int s0 = __shfl(sreg, i);
            int s1 = __shfl(sreg, i + 1);
            float l0 = es[(size_t)s0 * 8 + hB] + edl;
            float l1 = es[(size_t)s1 * 8 + hB] + edl;
            l0 = l0 > 0.f ? l0 : 0.2f * l0;
            l1 = l1 > 0.f ? l1 : 0.2f * l1;
            float w0 = __expf(l0), w1 = __expf(l1);
            half4 h0 = Hl[(size_t)s0 * 64];
            half4 h1 = Hl[(size_t)s1 * 64];
            a0 += w0 * (float)h0[0]; a1 += w0 * (float)h0[1];
            a2 += w0 * (float)h0[2]; a3 += w0 * (float)h0[3];
            a0 += w1 * (float)h1[0]; a1 += w1 * (float)h1[1];
            a2 += w1 * (float)h1[2]; a3 += w1 * (float)h1[3];
            den += w0 + w1;
        }
        if (i < rem) {
            int s0 = __shfl(sreg, i);
            float l0 = es[(size_t)s0 * 8 + hB] + edl;
            l0 = l0 > 0.f ? l0 : 0.2f * l0;
            float w0 = __expf(l0);
            half4 h0 = Hl[(size_t)s0 * 64];
            a0 += w0 * (float)h0[0]; a1 += w0 * (float)h0[1];
            a2 += w0 * (float)h0[2]; a3 += w0 * (float)h0[3];
            den += w0;
        }
    }

    float r = 1.f / (den + 1e-16f);
    float4 bb = ((const float4*)b1)[lane];
    float o0 = a0 * r + bb.x, o1 = a1 * r + bb.y;
    float o2 = a2 * r + bb.z, o3 = a3 * r + bb.w;
    o0 = o0 > 0.f ? o0 : __expf(o0) - 1.f;
    o1 = o1 > 0.f ? o1 : __expf(o1) - 1.f;
    o2 = o2 > 0.f ? o2 : __expf(o2) - 1.f;
    o3 = o3 > 0.f ? o3 : __expf(o3) - 1.f;
    ((half4*)(out1 + (size_t)n * 256))[lane] =
        (half4){(_Float16)o0, (_Float16)o1, (_Float16)o2, (_Float16)o3};

    // fused layer-2 attention coefficients
    float4 vs = ((const float4*)vs2)[lane];
    float4 vd = ((const float4*)vd2)[lane];
    float ps = o0 * vs.x + o1 * vs.y + o2 * vs.z + o3 * vs.w;
    float pd = o0 * vd.x + o1 * vd.y + o2 * vd.z + o3 * vd.w;
#pragma unroll
    for (int mk = 1; mk < 64; mk <<= 1) {
        ps += __shfl_xor(ps, mk, 64);
        pd += __shfl_xor(pd, mk, 64);
    }
    if (lane == 0) { es2[n] = ps; ed2[n] = pd; }
}

// ------------------------------------------------------------------
// Layer-2 aggregation: single-pass wave-per-node on out1 rows
// (linearity: (sum a*out1[s]) @ W2 == sum a*(out1@W2)[s]).
// ------------------------------------------------------------------
__global__ __launch_bounds__(256) void k_agg2(
    const _Float16* __restrict__ O1, const float* __restrict__ es2,
    const float* __restrict__ ed2, const int* __restrict__ offsets,
    const int* __restrict__ csr_src, _Float16* __restrict__ xagg) {
    int t = threadIdx.x, w = t >> 6, lane = t & 63;
    int n = blockIdx.x * 4 + w;
    int beg = offsets[n];
    int deg = offsets[n + 1] - beg;
    float edn = ed2[n];

    const half4* __restrict__ Ol = (const half4*)O1 + lane;
    float a0 = 0.f, a1 = 0.f, a2 = 0.f, a3 = 0.f, den = 0.f;

    for (int base = 0; base < deg; base += 64) {
        int rem = deg - base; if (rem > 64) rem = 64;
        int idx = beg + base + lane;
        if (idx >= E_TOT) idx = E_TOT - 1;
        int sreg = csr_src[idx];
        int i = 0;
        for (; i + 1 < rem; i += 2) {
            int s0 = __shfl(sreg, i);
            int s1 = __shfl(sreg, i + 1);
            float l0 = es2[s0] + edn;
            float l1 = es2[s1] + edn;
            l0 = l0 > 0.f ? l0 : 0.2f * l0;
            l1 = l1 > 0.f ? l1 : 0.2f * l1;
            float w0 = __expf(l0), w1 = __expf(l1);
            half4 h0 = Ol[(size_t)s0 * 64];
            half4 h1 = Ol[(size_t)s1 * 64];
            a0 += w0 * (float)h0[0]; a1 += w0 * (float)h0[1];
            a2 += w0 * (float)h0[2]; a3 += w0 * (float)h0[3];
            a0 += w1 * (float)h1[0]; a1 += w1 * (float)h1[1];
            a2 += w1 * (float)h1[2]; a3 += w1 * (float)h1[3];
            den += w0 + w1;
        }
        if (i < rem) {
            int s0 = __shfl(sreg, i);
            float l0 = es2[s0] + edn;
            l0 = l0 > 0.f ? l0 : 0.2f * l0;
            float w0 = __expf(l0);
            half4 h0 = Ol[(size_t)s0 * 64];
            a0 += w0 * (float)h0[0]; a1 += w0 * (float)h0[1];
            a2 += w0 * (float)h0[2]; a3 += w0 * (float)h0[3];
            den += w0;
        }
    }

    float r = 1.f / (den + 1e-16f);
    ((half4*)(xagg + (size_t)n * 256))[lane] =
        (half4){(_Float16)(a0 * r), (_Float16)(a1 * r),
                (_Float16)(a2 * r), (_Float16)(a3 * r)};
}

// ------------------------------------------------------------------
extern "C" void kernel_launch(void* const* d_in, const int* in_sizes, int n_in,
                              void* d_out, int out_size, void* d_ws, size_t ws_size,
                              hipStream_t stream) {
    const float* x   = (const float*)d_in[0];
    const int*   ei  = (const int*)d_in[1];
    const float* W1  = (const float*)d_in[2];
    const float* as1 = (const float*)d_in[3];
    const float* ad1 = (const float*)d_in[4];
    const float* b1  = (const float*)d_in[5];
    const float* W2  = (const float*)d_in[6];
    const float* as2 = (const float*)d_in[7];
    const float* ad2 = (const float*)d_in[8];
    const float* b2  = (const float*)d_in[9];
    float* out = (float*)d_out;

    char* ws = (char*)d_ws;
    size_t off = 0;
    auto alloc = [&](size_t bytes) {
        void* p = ws + off;
        off = (off + bytes + 255) & ~(size_t)255;
        return p;
    };
    _Float16* h1h     = (_Float16*)alloc((size_t)N_NODES * 256 * 2);
    _Float16* out1h   = (_Float16*)alloc((size_t)N_NODES * 256 * 2);
    _Float16* xagg    = (_Float16*)alloc((size_t)N_NODES * 256 * 2);
    _Float16* w1t     = (_Float16*)alloc((size_t)128 * 256 * 2);
    _Float16* w2t     = (_Float16*)alloc((size_t)256 * 256 * 2);
    float*    es1     = (float*)alloc((size_t)N_NODES * 8 * 4);
    float*    ed1     = (float*)alloc((size_t)N_NODES * 8 * 4);
    float*    es2     = (float*)alloc((size_t)N_NODES * 4);
    float*    ed2     = (float*)alloc((size_t)N_NODES * 4);
    float*    vs2     = (float*)alloc(256 * 4);
    float*    vd2     = (float*)alloc(256 * 4);
    int*      deg     = (int*)alloc((size_t)N_NODES * 4);
    int*      offsets = (int*)alloc((size_t)(N_NODES + 1) * 4);
    int*      cur     = (int*)alloc((size_t)N_NODES * 4);
    int*      csr_src = (int*)alloc((size_t)E_TOT * 4);
    int*      bsum    = (int*)alloc((size_t)NB * 4);
    int*      boff    = (int*)alloc((size_t)(NB + 1) * 4);

    const int TB = 256;
    int gridN = (N_NODES + TB - 1) / TB;
    int gridE = (E_TOT + TB - 1) / TB;
    int gridG = (N_NODES + 31) / 32;   // 32-row GEMM tiles
    int gridA = N_NODES / 4;           // wave-per-node

    // CSR build
    k_zero<<<gridN, TB, 0, stream>>>(deg, N_NODES);
    k_count<<<gridE, TB, 0, stream>>>(ei, deg);
    k_blocksum<<<NB, TB, 0, stream>>>(deg, bsum);
    k_scanbsum<<<1, TB, 0, stream>>>(bsum, boff);
    k_offsets<<<NB, TB, 0, stream>>>(deg, boff, offsets, cur);
    k_scatter<<<gridE, TB, 0, stream>>>(ei, cur, csr_src);

    // prep: W transposes + layer-2 attention vectors (one launch)
    int prepN = 128 * 256 + 256 * 256 + 256;
    k_prepw<<<(prepN + TB - 1) / TB, TB, 0, stream>>>(W1, W2, as2, ad2,
                                                      w1t, w2t, vs2, vd2);

    // layer 1 (X cast fused into gemm1)
    k_gemm1<<<gridG, TB, 0, stream>>>(x, w1t, as1, ad1, h1h, es1, ed1);
    k_agg1<<<gridA, TB, 0, stream>>>(h1h, es1, ed1, offsets, csr_src, b1,
                                     vs2, vd2, out1h, es2, ed2);

    // layer 2: aggregate first (linearity), then GEMM straight to d_out
    k_agg2<<<gridA, TB, 0, stream>>>(out1h, es2, ed2, offsets, csr_src, xagg);
    k_gemm2<<<gridG, TB, 0, stream>>>(xagg, w2t, b2, out);
}